// Round 1
// baseline (4429.908 us; speedup 1.0000x reference)
//
#include <hip/hip_runtime.h>
#include <hip/hip_bf16.h>

// Model: B=8, C=256, NH=8, DH=32, N=1024 (32x32), L=8, DFF=1025
// Workspace budget (floats): 2*8421376 + 7*2097152 + 262144 = 31,784,960 (~127 MB)

// ---------------- conv 3x3, pad 1, optional SiLU ----------------
__global__ __launch_bounds__(256) void k_conv3x3(
    const float* __restrict__ x, const float* __restrict__ w,
    float* __restrict__ y, int Ci, int Co, int Hi, int Wi,
    int Ho, int Wo, int stride, int dosilu)
{
  int s = blockIdx.x * 256 + threadIdx.x;   // spatial index, w-fastest
  int wo = s & (Wo - 1);                    // Wo is power of two
  int ho = s / Wo;
  int co0 = blockIdx.y << 2;                // 4 output channels per thread
  int b = blockIdx.z;
  float acc[4] = {0.f, 0.f, 0.f, 0.f};
  const float* xb = x + ((size_t)b * Ci) * Hi * Wi;
  const float* wbase = w + ((size_t)co0 * Ci) * 9;
  for (int ci = 0; ci < Ci; ++ci) {
    const float* xc = xb + (size_t)ci * Hi * Wi;
    const float* wc = wbase + (size_t)ci * 9;
    float wr[4][9];
#pragma unroll
    for (int j = 0; j < 4; ++j)
#pragma unroll
      for (int t = 0; t < 9; ++t)
        wr[j][t] = wc[(size_t)j * Ci * 9 + t];
#pragma unroll
    for (int kh = 0; kh < 3; ++kh) {
      int hi = ho * stride + kh - 1;
      if ((unsigned)hi >= (unsigned)Hi) continue;
      const float* xr = xc + (size_t)hi * Wi;
#pragma unroll
      for (int kw = 0; kw < 3; ++kw) {
        int wi = wo * stride + kw - 1;
        float xv = ((unsigned)wi < (unsigned)Wi) ? xr[wi] : 0.f;
#pragma unroll
        for (int j = 0; j < 4; ++j)
          acc[j] = fmaf(xv, wr[j][kh * 3 + kw], acc[j]);
      }
    }
  }
  size_t chs = (size_t)Ho * Wo;
  size_t ob = ((size_t)(b * Co + co0)) * chs + s;
#pragma unroll
  for (int j = 0; j < 4; ++j) {
    float vv = acc[j];
    if (dosilu) vv = vv / (1.f + __expf(-vv));
    y[ob + (size_t)j * chs] = vv;
  }
}

// ---------------- transpose (B,256,1024) -> (B,1024,256) ----------------
__global__ void k_cxn_to_nxc(const float* __restrict__ x, float* __restrict__ y)
{
  __shared__ float t[32][33];
  int b = blockIdx.z;
  int n0 = blockIdx.x * 32, c0 = blockIdx.y * 32;
  int tx = threadIdx.x, ty = threadIdx.y;
  t[ty][tx] = x[((size_t)(b * 256 + c0 + ty)) * 1024 + n0 + tx];
  __syncthreads();
  y[((size_t)(b * 1024 + n0 + ty)) * 256 + c0 + tx] = t[tx][ty];
}

// ---------------- transpose (B,1024,256) -> (B,256,1024) ----------------
__global__ void k_nxc_to_cxn(const float* __restrict__ x, float* __restrict__ y)
{
  __shared__ float t[32][33];
  int b = blockIdx.z;
  int c0 = blockIdx.x * 32, n0 = blockIdx.y * 32;
  int tx = threadIdx.x, ty = threadIdx.y;
  t[ty][tx] = x[((size_t)(b * 1024 + n0 + ty)) * 256 + c0 + tx];
  __syncthreads();
  y[((size_t)(b * 256 + c0 + ty)) * 1024 + n0 + tx] = t[tx][ty];
}

// ---------------- sine positional embedding (1024, 256) ----------------
__global__ __launch_bounds__(256) void k_pos(float* __restrict__ pos)
{
  int n = blockIdx.x, c = threadIdx.x;
  int ih = n >> 5, iw = n & 31;
  float coord = (c < 128) ? (float)(ih + 1) : (float)(iw + 1);
  int cc = c & 127;
  float e = (float)((cc >> 1) << 1) * (1.f / 128.f);
  float t = coord / powf(10000.f, e);
  pos[(n << 8) + c] = (cc & 1) ? cosf(t) : sinf(t);
}

// ---------------- qk_in = src + pos (broadcast over batch) ----------------
__global__ __launch_bounds__(256) void k_add_pos(
    const float* __restrict__ s, const float* __restrict__ p, float* __restrict__ o)
{
  int i = blockIdx.x * 256 + threadIdx.x;     // over 524288 float4
  float4 a = ((const float4*)s)[i];
  float4 pp = ((const float4*)p)[i & 65535];  // 262144 floats / 4
  a.x += pp.x; a.y += pp.y; a.z += pp.z; a.w += pp.w;
  ((float4*)o)[i] = a;
}

// ---------------- fp32 NT GEMM: C[M,N] = A[M,K] @ B[N,K]^T + bias ----------------
// act: 0 = none, 1 = relu
__global__ __launch_bounds__(256) void k_gemm_nt(
    const float* __restrict__ A, int lda,
    const float* __restrict__ Bw, int ldb,
    const float* __restrict__ bias,
    float* __restrict__ C, int ldc,
    int M, int N, int K, int act)
{
  __shared__ float As[16][68];
  __shared__ float Bs[16][68];
  int tid = threadIdx.x;
  int bm = blockIdx.x << 6;
  int bn = blockIdx.y << 6;
  int lr = tid >> 2;            // 0..63: tile row
  int lc = (tid & 3) << 2;      // 0,4,8,12: k start
  int tx = tid & 15, ty = tid >> 4;
  bool avec = (lda & 3) == 0, bvec = (ldb & 3) == 0;
  float acc[4][4] = {};
  int nkt = (K + 15) >> 4;
  for (int kt = 0; kt < nkt; ++kt) {
    int k0 = kt << 4;
    int rem = K - (k0 + lc);
    {
      const float* Ap = A + (size_t)(bm + lr) * lda + k0 + lc;
      float a0 = 0, a1 = 0, a2 = 0, a3 = 0;
      if (rem >= 4 && avec) { float4 t4 = *(const float4*)Ap; a0 = t4.x; a1 = t4.y; a2 = t4.z; a3 = t4.w; }
      else { if (rem > 0) a0 = Ap[0]; if (rem > 1) a1 = Ap[1]; if (rem > 2) a2 = Ap[2]; if (rem > 3) a3 = Ap[3]; }
      As[lc + 0][lr] = a0; As[lc + 1][lr] = a1; As[lc + 2][lr] = a2; As[lc + 3][lr] = a3;
    }
    {
      int brow = bn + lr;
      float b0 = 0, b1 = 0, b2 = 0, b3 = 0;
      if (brow < N) {
        const float* Bp = Bw + (size_t)brow * ldb + k0 + lc;
        if (rem >= 4 && bvec) { float4 t4 = *(const float4*)Bp; b0 = t4.x; b1 = t4.y; b2 = t4.z; b3 = t4.w; }
        else { if (rem > 0) b0 = Bp[0]; if (rem > 1) b1 = Bp[1]; if (rem > 2) b2 = Bp[2]; if (rem > 3) b3 = Bp[3]; }
      }
      Bs[lc + 0][lr] = b0; Bs[lc + 1][lr] = b1; Bs[lc + 2][lr] = b2; Bs[lc + 3][lr] = b3;
    }
    __syncthreads();
#pragma unroll
    for (int kk = 0; kk < 16; ++kk) {
      float4 av = *(const float4*)&As[kk][ty << 2];
      float4 bv = *(const float4*)&Bs[kk][tx << 2];
      float a4[4] = {av.x, av.y, av.z, av.w};
      float b4[4] = {bv.x, bv.y, bv.z, bv.w};
#pragma unroll
      for (int i = 0; i < 4; ++i)
#pragma unroll
        for (int j = 0; j < 4; ++j)
          acc[i][j] = fmaf(a4[i], b4[j], acc[i][j]);
    }
    __syncthreads();
  }
#pragma unroll
  for (int i = 0; i < 4; ++i) {
    int row = bm + (ty << 2) + i;   // M is a multiple of 64 -> always valid
#pragma unroll
    for (int j = 0; j < 4; ++j) {
      int col = bn + (tx << 2) + j;
      if (col < N) {
        float v = acc[i][j] + bias[col];
        if (act == 1) v = fmaxf(v, 0.f);
        C[(size_t)row * ldc + col] = v;
      }
    }
  }
}

// ---------------- neighborhood attention (7x7 window, online softmax) ----------------
// q,k,v,ctx: (B*1024, 256) with channel = head*32 + d. Masked-out keys give
// exp(-1e9-...)==0 in the reference fp32 softmax, so skipping them is exact.
__global__ __launch_bounds__(256) void k_attn(
    const float* __restrict__ q, const float* __restrict__ k,
    const float* __restrict__ v, float* __restrict__ ctx)
{
  int bn = blockIdx.x;
  int b = bn >> 10, n = bn & 1023;
  int ih = n >> 5, iw = n & 31;
  int g = threadIdx.x >> 5;   // head (8 half-wave groups)
  int l = threadIdx.x & 31;   // dim within head
  const float scale = 0.17677669529663687f;  // 1/sqrt(32)
  float qd = q[((size_t)bn << 8) + (g << 5) + l] * scale;
  float m_run = -1e30f, l_run = 0.f, acc = 0.f;
  int h0 = max(ih - 3, 0), h1 = min(ih + 3, 31);
  int w0 = max(iw - 3, 0), w1 = min(iw + 3, 31);
  for (int mh = h0; mh <= h1; ++mh) {
    for (int mw = w0; mw <= w1; ++mw) {
      size_t moff = (((size_t)((b << 10) + (mh << 5) + mw)) << 8) + (g << 5) + l;
      float s = qd * k[moff];
      s += __shfl_xor(s, 1); s += __shfl_xor(s, 2); s += __shfl_xor(s, 4);
      s += __shfl_xor(s, 8); s += __shfl_xor(s, 16);
      float mn = fmaxf(m_run, s);
      float p = __expf(s - mn);
      float corr = __expf(m_run - mn);
      l_run = l_run * corr + p;
      acc = acc * corr + p * v[moff];
      m_run = mn;
    }
  }
  ctx[((size_t)bn << 8) + (g << 5) + l] = acc / l_run;
}

// ---------------- fused residual add + LayerNorm (in-place on s) ----------------
__global__ __launch_bounds__(256) void k_add_ln(
    float* __restrict__ s, const float* __restrict__ d,
    const float* __restrict__ g, const float* __restrict__ b)
{
  int row = blockIdx.x, c = threadIdx.x;
  size_t idx = ((size_t)row << 8) + c;
  float x = s[idx] + d[idx];
  __shared__ float red[4];
  float t = x;
  t += __shfl_xor(t, 1); t += __shfl_xor(t, 2); t += __shfl_xor(t, 4);
  t += __shfl_xor(t, 8); t += __shfl_xor(t, 16); t += __shfl_xor(t, 32);
  if ((c & 63) == 0) red[c >> 6] = t;
  __syncthreads();
  float mu = (red[0] + red[1] + red[2] + red[3]) * (1.f / 256.f);
  float dx = x - mu;
  float u = dx * dx;
  __syncthreads();
  u += __shfl_xor(u, 1); u += __shfl_xor(u, 2); u += __shfl_xor(u, 4);
  u += __shfl_xor(u, 8); u += __shfl_xor(u, 16); u += __shfl_xor(u, 32);
  if ((c & 63) == 0) red[c >> 6] = u;
  __syncthreads();
  float var = (red[0] + red[1] + red[2] + red[3]) * (1.f / 256.f);
  float r = rsqrtf(var + 1e-5f);
  s[idx] = dx * r * g[c] + b[c];
}

extern "C" void kernel_launch(void* const* d_in, const int* in_sizes, int n_in,
                              void* d_out, int out_size, void* d_ws, size_t ws_size,
                              hipStream_t stream)
{
  const float* hint = (const float*)d_in[0];
  const float* cw[8];
  for (int i = 0; i < 8; ++i) cw[i] = (const float*)d_in[1 + i];
  const float* ipw  = (const float*)d_in[9];
  const float* ipb  = (const float*)d_in[10];
  const float* outw = (const float*)d_in[11];
  const float* outb = (const float*)d_in[12];
  const float* l1w  = (const float*)d_in[13];
  const float* l1b  = (const float*)d_in[14];
  const float* l2w  = (const float*)d_in[15];
  const float* l2b  = (const float*)d_in[16];
  const float* g1   = (const float*)d_in[17];
  const float* b1   = (const float*)d_in[18];
  const float* g2   = (const float*)d_in[19];
  const float* b2   = (const float*)d_in[20];

  float* ws = (float*)d_ws;
  size_t off = 0;
  float* bufA = ws + off; off += 8421376;   // conv ping; later ff (8192 x 1028 padded)
  float* bufB = ws + off; off += 8421376;   // conv pong
  float* src  = ws + off; off += 2097152;   // (8*1024, 256)
  float* qkin = ws + off; off += 2097152;
  float* qb   = ws + off; off += 2097152;
  float* kb   = ws + off; off += 2097152;
  float* vb   = ws + off; off += 2097152;
  float* ctx  = ws + off; off += 2097152;
  float* tmp  = ws + off; off += 2097152;
  float* pos  = ws + off; off += 262144;    // (1024, 256)

  // ---- conv stack ----
  const int Cis[8]  = {3, 16, 16, 32, 32, 96, 96, 256};
  const int Cos[8]  = {16, 16, 32, 32, 96, 96, 256, 256};
  const int His[8]  = {256, 256, 256, 128, 128, 64, 64, 32};
  const int Strd[8] = {1, 1, 2, 1, 2, 1, 2, 1};
  const float* cin = hint;
  float* pp[2] = {bufA, bufB};
  for (int i = 0; i < 8; ++i) {
    int Hi = His[i], Wi = Hi;
    int Ho = Hi / Strd[i], Wo = Ho;
    float* coutp = pp[i & 1];
    dim3 grid(Ho * Wo / 256, Cos[i] / 4, 8);
    k_conv3x3<<<grid, 256, 0, stream>>>(cin, cw[i], coutp, Cis[i], Cos[i],
                                        Hi, Wi, Ho, Wo, Strd[i], (i < 7) ? 1 : 0);
    cin = coutp;
  }
  // conv7 out in bufB: (8,256,1024) -> src (8,1024,256)
  k_cxn_to_nxc<<<dim3(32, 8, 8), dim3(32, 32), 0, stream>>>(bufB, src);
  k_pos<<<dim3(1024), dim3(256), 0, stream>>>(pos);

  // ---- transformer layers ----
  for (int l = 0; l < 8; ++l) {
    const float* ipw_l  = ipw  + (size_t)l * 768 * 256;
    const float* ipb_l  = ipb  + (size_t)l * 768;
    const float* outw_l = outw + (size_t)l * 256 * 256;
    const float* outb_l = outb + (size_t)l * 256;
    const float* l1w_l  = l1w  + (size_t)l * 1025 * 256;
    const float* l1b_l  = l1b  + (size_t)l * 1025;
    const float* l2w_l  = l2w  + (size_t)l * 256 * 1025;
    const float* l2b_l  = l2b  + (size_t)l * 256;
    const float* g1_l = g1 + l * 256; const float* b1_l = b1 + l * 256;
    const float* g2_l = g2 + l * 256; const float* b2_l = b2 + l * 256;

    k_add_pos<<<dim3(2048), 256, 0, stream>>>(src, pos, qkin);
    dim3 gq(128, 4);
    k_gemm_nt<<<gq, 256, 0, stream>>>(qkin, 256, ipw_l,          256, ipb_l,       qb, 256, 8192, 256, 256, 0);
    k_gemm_nt<<<gq, 256, 0, stream>>>(qkin, 256, ipw_l + 65536,  256, ipb_l + 256, kb, 256, 8192, 256, 256, 0);
    k_gemm_nt<<<gq, 256, 0, stream>>>(src,  256, ipw_l + 131072, 256, ipb_l + 512, vb, 256, 8192, 256, 256, 0);
    k_attn<<<dim3(8192), 256, 0, stream>>>(qb, kb, vb, ctx);
    k_gemm_nt<<<gq, 256, 0, stream>>>(ctx, 256, outw_l, 256, outb_l, tmp, 256, 8192, 256, 256, 0);
    k_add_ln<<<dim3(8192), 256, 0, stream>>>(src, tmp, g1_l, b1_l);
    k_gemm_nt<<<dim3(128, 17), 256, 0, stream>>>(src, 256, l1w_l, 256, l1b_l, bufA, 1028, 8192, 1025, 256, 1);
    k_gemm_nt<<<gq, 256, 0, stream>>>(bufA, 1028, l2w_l, 1025, l2b_l, tmp, 256, 8192, 256, 1025, 0);
    k_add_ln<<<dim3(8192), 256, 0, stream>>>(src, tmp, g2_l, b2_l);
  }

  // ---- output: (8,1024,256) -> (8,256,32,32) ----
  k_nxc_to_cxn<<<dim3(8, 32, 8), dim3(32, 32), 0, stream>>>(src, (float*)d_out);
}

// Round 2
// 2653.223 us; speedup vs baseline: 1.6696x; 1.6696x over previous
//
#include <hip/hip_runtime.h>
#include <hip/hip_bf16.h>

// B=8, C=256, NH=8, DH=32, N=1024 (32x32), L=8, DFF=1025 (pad 1152)
// Convs 0-3: direct fp32 (4-wide). Convs 4-7: im2col + bf16 MFMA GEMM.
// Transformer: bf16 MFMA GEMMs, fp32 residual/LN, exact-sparse 7x7 attention.

typedef __bf16 bf16x8 __attribute__((ext_vector_type(8)));
typedef float f32x4 __attribute__((ext_vector_type(4)));

__device__ __forceinline__ unsigned short f2bf(float f) {
  unsigned int u = __float_as_uint(f);
  unsigned int r = (u + 0x7fffu + ((u >> 16) & 1u)) >> 16;
  return (unsigned short)r;
}
__device__ __forceinline__ float bf2f(unsigned short h) {
  return __uint_as_float(((unsigned int)h) << 16);
}

// ---------------- direct conv 3x3, 4 spatial x 4 co per thread ----------------
template<int STRIDE>
__global__ __launch_bounds__(256) void k_conv3x3_p4(
    const float* __restrict__ x, const float* __restrict__ w,
    float* __restrict__ y, int Ci, int Co, int Hi, int Wi, int Ho, int Wo, int dosilu)
{
  int s4 = blockIdx.x * 256 + threadIdx.x;   // over Ho * (Wo/4)
  int Wq = Wo >> 2;
  int wo0 = (s4 & (Wq - 1)) << 2;            // Wq is pow2
  int ho = s4 / Wq;
  int co0 = blockIdx.y << 2;
  int b = blockIdx.z;
  const int NX = 3 * STRIDE + 3;             // 6 (s1) or 9 (s2)
  float acc[4][4] = {};                      // [co][pos]
  const float* xb = x + (size_t)b * Ci * Hi * Wi;
  const float* wb = w + (size_t)co0 * Ci * 9;
  for (int ci = 0; ci < Ci; ++ci) {
    const float* xc = xb + (size_t)ci * Hi * Wi;
    const float* wc = wb + (size_t)ci * 9;
    float wr[4][9];
#pragma unroll
    for (int j = 0; j < 4; ++j)
#pragma unroll
      for (int t = 0; t < 9; ++t)
        wr[j][t] = wc[(size_t)j * Ci * 9 + t];
#pragma unroll
    for (int kh = 0; kh < 3; ++kh) {
      int hi = ho * STRIDE + kh - 1;
      if ((unsigned)hi >= (unsigned)Hi) continue;
      const float* xr = xc + (size_t)hi * Wi;
      float xv[NX];
#pragma unroll
      for (int u = 0; u < NX; ++u) {
        int wi = wo0 * STRIDE - 1 + u;
        xv[u] = ((unsigned)wi < (unsigned)Wi) ? xr[wi] : 0.f;
      }
#pragma unroll
      for (int p = 0; p < 4; ++p)
#pragma unroll
        for (int kw = 0; kw < 3; ++kw) {
          float xs = xv[p * STRIDE + kw];
#pragma unroll
          for (int j = 0; j < 4; ++j)
            acc[j][p] = fmaf(xs, wr[j][kh * 3 + kw], acc[j][p]);
        }
    }
  }
  size_t chs = (size_t)Ho * Wo;
  size_t base = ((size_t)(b * Co + co0)) * chs + (size_t)ho * Wo + wo0;
#pragma unroll
  for (int j = 0; j < 4; ++j)
#pragma unroll
    for (int p = 0; p < 4; ++p) {
      float vv = acc[j][p];
      if (dosilu) vv = vv / (1.f + __expf(-vv));
      y[base + (size_t)j * chs + p] = vv;
    }
}

// ---------------- im2col: src (NCHW f32 | NHWC f32 | NHWC bf16) -> [rows][Kpad] bf16 ----
__global__ __launch_bounds__(256) void k_im2col(
    const void* __restrict__ src, int f32, int nchw, unsigned short* __restrict__ dst,
    int Ci, int Hi, int Wi, int Ho, int Wo, int stride, int Kpad, int row0)
{
  int r = blockIdx.x;
  int pos = row0 + r;
  int wo = pos % Wo; int t2 = pos / Wo; int ho = t2 % Ho; int b = t2 / Ho;
  int K9 = 9 * Ci;
  for (int e = threadIdx.x; e < Kpad; e += 256) {
    unsigned short val = 0;
    if (e < K9) {
      int t = e / Ci, ci = e - t * Ci;
      int hi = ho * stride + (t / 3) - 1;
      int wi = wo * stride + (t % 3) - 1;
      if ((unsigned)hi < (unsigned)Hi && (unsigned)wi < (unsigned)Wi) {
        size_t so = nchw ? ((((size_t)b * Ci + ci) * Hi + hi) * Wi + wi)
                         : ((((size_t)b * Hi + hi) * Wi + wi) * Ci + ci);
        val = f32 ? f2bf(((const float*)src)[so]) : ((const unsigned short*)src)[so];
      }
    }
    dst[(size_t)r * Kpad + e] = val;
  }
}

// ---------------- conv weight permute: OIHW -> [CoP][t*Ci+ci] bf16, zero-padded ----
__global__ __launch_bounds__(256) void k_wperm(
    const float* __restrict__ w, unsigned short* __restrict__ wp,
    int Co, int Ci, int CoP, int Kpad)
{
  int idx = blockIdx.x * 256 + threadIdx.x;
  if (idx >= CoP * Kpad) return;
  int co = idx / Kpad, k = idx - co * Kpad;
  float v = 0.f;
  if (co < Co && k < 9 * Ci) {
    int t = k / Ci, ci = k - t * Ci;
    v = w[((size_t)co * Ci + ci) * 9 + t];
  }
  wp[idx] = f2bf(v);
}

// ---------------- pad-convert fp32 -> bf16 (and/or padded fp32), per layer slab ----
__global__ void k_cvt_pad(const float* __restrict__ in, unsigned short* __restrict__ outb,
                          float* __restrict__ outf, int R, int C, int Rp, int Cp)
{
  int l = blockIdx.y;
  int total = Rp * Cp;
  for (int idx = blockIdx.x * 256 + threadIdx.x; idx < total; idx += gridDim.x * 256) {
    int r = idx / Cp, c = idx - r * Cp;
    float v = (r < R && c < C) ? in[((size_t)l * R + r) * C + c] : 0.f;
    size_t o = (size_t)l * total + idx;
    if (outb) outb[o] = f2bf(v);
    if (outf) outf[o] = v;
  }
}

// ---------------- bf16 MFMA GEMM: C[M,N] = A[M,K] @ B[N,K]^T (+bias, act) ----------
// BM=BN=128, BK=32, 4 waves (2x2), wave tile 64x64. M%128==0, Npad%128==0, K%32==0.
// act: 0 none, 1 relu, 2 silu. omode: 0 f32, 1 bf16, 2 both.
__global__ __launch_bounds__(256) void k_gemm_bf16(
    const unsigned short* __restrict__ A, int lda,
    const unsigned short* __restrict__ Bw, int ldb,
    const float* __restrict__ bias,
    float* __restrict__ C, unsigned short* __restrict__ Cb, int ldc,
    int M, int K, int Nstore, int act, int omode)
{
  __shared__ unsigned short lA[2][128 * 32];
  __shared__ unsigned short lB[2][128 * 32];
  int tid = threadIdx.x, lane = tid & 63, wid = tid >> 6;
  int bm = blockIdx.x << 7, bn = blockIdx.y << 7;
  int wm = wid >> 1, wn = wid & 1;
  f32x4 acc[4][4];
#pragma unroll
  for (int m = 0; m < 4; ++m)
#pragma unroll
    for (int n = 0; n < 4; ++n)
#pragma unroll
      for (int j = 0; j < 4; ++j) acc[m][n][j] = 0.f;

  int crow = lane >> 2;              // 0..15 within chunk
  int ckof = (lane & 3) << 3;        // k element offset 0,8,16,24
  const unsigned short* Abase = A + (size_t)bm * lda + ckof;
  const unsigned short* Bbase = Bw + (size_t)bn * ldb + ckof;
  int nkt = K >> 5;
  int cur = 0;

#define STAGE(buf, kt)                                                               \
  {                                                                                  \
    int k0s = (kt) << 5;                                                             \
    _Pragma("unroll")                                                                \
    for (int i = 0; i < 2; ++i) {                                                    \
      int c = wid * 2 + i;                                                           \
      int row = c * 16 + crow;                                                       \
      __builtin_amdgcn_global_load_lds(                                              \
          (const __attribute__((address_space(1))) unsigned int*)(Abase + (size_t)row * lda + k0s), \
          (__attribute__((address_space(3))) unsigned int*)(&lA[buf][c * 512]), 16, 0, 0); \
      __builtin_amdgcn_global_load_lds(                                              \
          (const __attribute__((address_space(1))) unsigned int*)(Bbase + (size_t)row * ldb + k0s), \
          (__attribute__((address_space(3))) unsigned int*)(&lB[buf][c * 512]), 16, 0, 0); \
    }                                                                                \
  }

  STAGE(0, 0)
  int r0 = wm * 64 + (lane & 15);
  int c0 = wn * 64 + (lane & 15);
  int kq = (lane >> 4) << 3;
  for (int kt = 0; kt < nkt; ++kt) {
    __syncthreads();   // drains vmcnt (staged tile ready) + lgkm (prev reads done)
    if (kt + 1 < nkt) STAGE(cur ^ 1, kt + 1)
    bf16x8 af[4], bfr[4];
#pragma unroll
    for (int m = 0; m < 4; ++m)
      af[m] = *(const bf16x8*)&lA[cur][(r0 + m * 16) * 32 + kq];
#pragma unroll
    for (int n = 0; n < 4; ++n)
      bfr[n] = *(const bf16x8*)&lB[cur][(c0 + n * 16) * 32 + kq];
#pragma unroll
    for (int m = 0; m < 4; ++m)
#pragma unroll
      for (int n = 0; n < 4; ++n)
        acc[m][n] = __builtin_amdgcn_mfma_f32_16x16x32_bf16(af[m], bfr[n], acc[m][n], 0, 0, 0);
    cur ^= 1;
  }
#undef STAGE

  int colb = bn + wn * 64 + (lane & 15);
  int rowb = bm + wm * 64 + ((lane >> 4) << 2);
#pragma unroll
  for (int n = 0; n < 4; ++n) {
    int col = colb + n * 16;
    if (col >= Nstore) continue;
    float bs = bias ? bias[col] : 0.f;
#pragma unroll
    for (int m = 0; m < 4; ++m) {
#pragma unroll
      for (int j = 0; j < 4; ++j) {
        int row = rowb + m * 16 + j;
        float v = acc[m][n][j] + bs;
        if (act == 1) v = fmaxf(v, 0.f);
        else if (act == 2) v = v / (1.f + __expf(-v));
        size_t off = (size_t)row * ldc + col;
        if (omode == 0) C[off] = v;
        else if (omode == 1) Cb[off] = f2bf(v);
        else { C[off] = v; Cb[off] = f2bf(v); }
      }
    }
  }
}

// ---------------- sine positional embedding (1024, 256) fp32 ----------------
__global__ __launch_bounds__(256) void k_pos(float* __restrict__ pos)
{
  int n = blockIdx.x, c = threadIdx.x;
  int ih = n >> 5, iw = n & 31;
  float coord = (c < 128) ? (float)(ih + 1) : (float)(iw + 1);
  int cc = c & 127;
  float e = (float)((cc >> 1) << 1) * (1.f / 128.f);
  float t = coord / powf(10000.f, e);
  pos[(n << 8) + c] = (cc & 1) ? cosf(t) : sinf(t);
}

// ---------------- qkin = bf16(src + pos) ----------------
__global__ __launch_bounds__(256) void k_add_pos(
    const float* __restrict__ s, const float* __restrict__ p, unsigned short* __restrict__ o)
{
  int i = blockIdx.x * 256 + threadIdx.x;       // over 524288 groups of 4
  float4 a = ((const float4*)s)[i];
  float4 pp = ((const float4*)p)[i & 65535];
  ushort4 r;
  r.x = f2bf(a.x + pp.x); r.y = f2bf(a.y + pp.y);
  r.z = f2bf(a.z + pp.z); r.w = f2bf(a.w + pp.w);
  ((ushort4*)o)[i] = r;
}

// ---------------- neighborhood attention (7x7), bf16 in/out, fp32 math ----------
__global__ __launch_bounds__(256) void k_attn(
    const unsigned short* __restrict__ qk, const unsigned short* __restrict__ v,
    unsigned short* __restrict__ ctx)
{
  int bn = blockIdx.x;
  int b = bn >> 10, n = bn & 1023;
  int ih = n >> 5, iw = n & 31;
  int g = threadIdx.x >> 5;   // head
  int l = threadIdx.x & 31;   // dim
  const float scale = 0.17677669529663687f;  // 1/sqrt(32)
  float qd = bf2f(qk[((size_t)bn << 9) + (g << 5) + l]) * scale;
  float m_run = -1e30f, l_run = 0.f, acc = 0.f;
  int h0 = max(ih - 3, 0), h1 = min(ih + 3, 31);
  int w0 = max(iw - 3, 0), w1 = min(iw + 3, 31);
  for (int mh = h0; mh <= h1; ++mh) {
    for (int mw = w0; mw <= w1; ++mw) {
      size_t mpos = (size_t)((b << 10) + (mh << 5) + mw);
      float s = qd * bf2f(qk[(mpos << 9) + 256 + (g << 5) + l]);
      s += __shfl_xor(s, 1); s += __shfl_xor(s, 2); s += __shfl_xor(s, 4);
      s += __shfl_xor(s, 8); s += __shfl_xor(s, 16);
      float mn = fmaxf(m_run, s);
      float p = __expf(s - mn);
      float corr = __expf(m_run - mn);
      l_run = l_run * corr + p;
      acc = acc * corr + p * bf2f(v[(mpos << 8) + (g << 5) + l]);
      m_run = mn;
    }
  }
  ctx[((size_t)bn << 8) + (g << 5) + l] = f2bf(acc / l_run);
}

// ---------------- fused residual add + LayerNorm -> src (f32) + srcb (bf16) ------
__global__ __launch_bounds__(256) void k_add_ln(
    float* __restrict__ s, unsigned short* __restrict__ sb, const float* __restrict__ d,
    const float* __restrict__ g, const float* __restrict__ b)
{
  int row = blockIdx.x, c = threadIdx.x;
  size_t idx = ((size_t)row << 8) + c;
  float x = s[idx] + d[idx];
  __shared__ float red[4];
  float t = x;
  t += __shfl_xor(t, 1); t += __shfl_xor(t, 2); t += __shfl_xor(t, 4);
  t += __shfl_xor(t, 8); t += __shfl_xor(t, 16); t += __shfl_xor(t, 32);
  if ((c & 63) == 0) red[c >> 6] = t;
  __syncthreads();
  float mu = (red[0] + red[1] + red[2] + red[3]) * (1.f / 256.f);
  float dx = x - mu;
  float u = dx * dx;
  __syncthreads();
  u += __shfl_xor(u, 1); u += __shfl_xor(u, 2); u += __shfl_xor(u, 4);
  u += __shfl_xor(u, 8); u += __shfl_xor(u, 16); u += __shfl_xor(u, 32);
  if ((c & 63) == 0) red[c >> 6] = u;
  __syncthreads();
  float var = (red[0] + red[1] + red[2] + red[3]) * (1.f / 256.f);
  float r = rsqrtf(var + 1e-5f);
  float o = dx * r * g[c] + b[c];
  s[idx] = o;
  sb[idx] = f2bf(o);
}

// ---------------- (B,1024,256) f32 -> (B,256,32,32) ----------------
__global__ void k_nxc_to_cxn(const float* __restrict__ x, float* __restrict__ y)
{
  __shared__ float t[32][33];
  int b = blockIdx.z;
  int c0 = blockIdx.x * 32, n0 = blockIdx.y * 32;
  int tx = threadIdx.x, ty = threadIdx.y;
  t[ty][tx] = x[((size_t)(b * 1024 + n0 + ty)) * 256 + c0 + tx];
  __syncthreads();
  y[((size_t)(b * 256 + c0 + ty)) * 1024 + n0 + tx] = t[tx][ty];
}

extern "C" void kernel_launch(void* const* d_in, const int* in_sizes, int n_in,
                              void* d_out, int out_size, void* d_ws, size_t ws_size,
                              hipStream_t stream)
{
  const float* hint = (const float*)d_in[0];
  const float* cw[8];
  for (int i = 0; i < 8; ++i) cw[i] = (const float*)d_in[1 + i];
  const float* ipw  = (const float*)d_in[9];
  const float* ipb  = (const float*)d_in[10];
  const float* outw = (const float*)d_in[11];
  const float* outb = (const float*)d_in[12];
  const float* l1w  = (const float*)d_in[13];
  const float* l1b  = (const float*)d_in[14];
  const float* l2w  = (const float*)d_in[15];
  const float* l2b  = (const float*)d_in[16];
  const float* g1   = (const float*)d_in[17];
  const float* b1   = (const float*)d_in[18];
  const float* g2   = (const float*)d_in[19];
  const float* b2   = (const float*)d_in[20];

  float* ws = (float*)d_ws;
  size_t off = 0;
  float* bufA = ws + off; off += 8421376;                 // conv ping / qkin,vb,ctx,tmp
  float* bufB = ws + off; off += 8421376;                 // conv pong / qk buffer
  float* im2A = ws + off; off += 4718592;                 // im2col chunks / ff
  float* src  = ws + off; off += 2097152;                 // (8192, 256) f32
  unsigned short* srcb = (unsigned short*)(ws + off); off += 1048576;
  float* pos  = ws + off; off += 262144;
  unsigned short* wqkvb = (unsigned short*)(ws + off); off += 786432;   // 8 x 768 x 256
  unsigned short* outwb = (unsigned short*)(ws + off); off += 262144;   // 8 x 256 x 256
  unsigned short* l1wb  = (unsigned short*)(ws + off); off += 1179648;  // 8 x 1152 x 256
  unsigned short* l2wb  = (unsigned short*)(ws + off); off += 1179648;  // 8 x 256 x 1152
  unsigned short* cwp4  = (unsigned short*)(ws + off); off += 18432;    // 128 x 288
  unsigned short* cwp5  = (unsigned short*)(ws + off); off += 55296;    // 128 x 864
  unsigned short* cwp6  = (unsigned short*)(ws + off); off += 110592;   // 256 x 864
  unsigned short* cwp7  = (unsigned short*)(ws + off); off += 294912;   // 256 x 2304
  float* l1bp = ws + off; off += 9216;                    // 8 x 1152 f32

  // in-transformer overlays
  unsigned short* qkin = (unsigned short*)(bufA + 0);
  unsigned short* vb   = (unsigned short*)(bufA + 1048576);
  unsigned short* ctx  = (unsigned short*)(bufA + 2097152);
  float* tmp           = bufA + 3145728;
  unsigned short* qkb  = (unsigned short*)(bufB + 0);     // (8192, 512) bf16
  unsigned short* ff   = (unsigned short*)im2A;           // (8192, 1152) bf16

  // ---- weight conversions ----
  k_cvt_pad<<<dim3(768, 8), 256, 0, stream>>>(ipw,  wqkvb, nullptr, 768, 256, 768, 256);
  k_cvt_pad<<<dim3(256, 8), 256, 0, stream>>>(outw, outwb, nullptr, 256, 256, 256, 256);
  k_cvt_pad<<<dim3(1152, 8), 256, 0, stream>>>(l1w, l1wb, nullptr, 1025, 256, 1152, 256);
  k_cvt_pad<<<dim3(1152, 8), 256, 0, stream>>>(l2w, l2wb, nullptr, 256, 1025, 256, 1152);
  k_cvt_pad<<<dim3(5, 8), 256, 0, stream>>>(l1b, nullptr, l1bp, 1025, 1, 1152, 1);
  k_wperm<<<144, 256, 0, stream>>>(cw[4], cwp4, 96, 32, 128, 288);
  k_wperm<<<432, 256, 0, stream>>>(cw[5], cwp5, 96, 96, 128, 864);
  k_wperm<<<864, 256, 0, stream>>>(cw[6], cwp6, 256, 96, 256, 864);
  k_wperm<<<2304, 256, 0, stream>>>(cw[7], cwp7, 256, 256, 256, 2304);

  // ---- convs 0-3 direct ----
  k_conv3x3_p4<1><<<dim3(64, 4, 8), 256, 0, stream>>>(hint, cw[0], bufA, 3, 16, 256, 256, 256, 256, 1);
  k_conv3x3_p4<1><<<dim3(64, 4, 8), 256, 0, stream>>>(bufA, cw[1], bufB, 16, 16, 256, 256, 256, 256, 1);
  k_conv3x3_p4<2><<<dim3(16, 8, 8), 256, 0, stream>>>(bufB, cw[2], bufA, 16, 32, 256, 256, 128, 128, 1);
  k_conv3x3_p4<1><<<dim3(16, 8, 8), 256, 0, stream>>>(bufA, cw[3], bufB, 32, 32, 128, 128, 128, 128, 1);

  // ---- conv4: NCHW f32 in bufB -> NHWC bf16 c4out in bufB (after im2col) ----
  unsigned short* c4out = (unsigned short*)bufB;
  unsigned short* im2u = (unsigned short*)im2A;
  k_im2col<<<32768, 256, 0, stream>>>(bufB, 1, 1, im2u, 32, 128, 128, 64, 64, 2, 288, 0);
  k_gemm_bf16<<<dim3(256, 1), 256, 0, stream>>>(im2u, 288, cwp4, 288, nullptr,
                                                nullptr, c4out, 96, 32768, 288, 96, 2, 1);
  // ---- conv5: 4 chunks of 8192 rows -> c5out in bufA ----
  unsigned short* c5out = (unsigned short*)bufA;
  for (int c = 0; c < 4; ++c) {
    k_im2col<<<8192, 256, 0, stream>>>(c4out, 0, 0, im2u, 96, 64, 64, 64, 64, 1, 864, c * 8192);
    k_gemm_bf16<<<dim3(64, 1), 256, 0, stream>>>(im2u, 864, cwp5, 864, nullptr,
                                                 nullptr, c5out + (size_t)c * 8192 * 96, 96,
                                                 8192, 864, 96, 2, 1);
  }
  // ---- conv6 -> c6out in bufB ----
  unsigned short* c6out = (unsigned short*)bufB;
  k_im2col<<<8192, 256, 0, stream>>>(c5out, 0, 0, im2u, 96, 64, 64, 32, 32, 2, 864, 0);
  k_gemm_bf16<<<dim3(64, 2), 256, 0, stream>>>(im2u, 864, cwp6, 864, nullptr,
                                               nullptr, c6out, 256, 8192, 864, 256, 2, 1);
  // ---- conv7: 2 chunks of 4096 rows -> src (f32) + srcb (bf16) directly ----
  for (int c = 0; c < 2; ++c) {
    k_im2col<<<4096, 256, 0, stream>>>(c6out, 0, 0, im2u, 256, 32, 32, 32, 32, 1, 2304, c * 4096);
    k_gemm_bf16<<<dim3(32, 2), 256, 0, stream>>>(im2u, 2304, cwp7, 2304, nullptr,
                                                 src + (size_t)c * 4096 * 256,
                                                 srcb + (size_t)c * 4096 * 256, 256,
                                                 4096, 2304, 256, 0, 2);
  }

  k_pos<<<dim3(1024), 256, 0, stream>>>(pos);

  // ---- transformer layers ----
  for (int l = 0; l < 8; ++l) {
    const unsigned short* wqkv_l = wqkvb + (size_t)l * 768 * 256;
    const float* ipb_l  = ipb  + (size_t)l * 768;
    const unsigned short* outw_l = outwb + (size_t)l * 256 * 256;
    const float* outb_l = outb + (size_t)l * 256;
    const unsigned short* l1w_l = l1wb + (size_t)l * 1152 * 256;
    const float* l1b_l  = l1bp + (size_t)l * 1152;
    const unsigned short* l2w_l = l2wb + (size_t)l * 256 * 1152;
    const float* l2b_l  = l2b  + (size_t)l * 256;
    const float* g1_l = g1 + l * 256; const float* b1_l = b1 + l * 256;
    const float* g2_l = g2 + l * 256; const float* b2_l = b2 + l * 256;

    k_add_pos<<<dim3(2048), 256, 0, stream>>>(src, pos, qkin);
    // q,k in one GEMM: N=512
    k_gemm_bf16<<<dim3(64, 4), 256, 0, stream>>>(qkin, 256, wqkv_l, 256, ipb_l,
                                                 nullptr, qkb, 512, 8192, 256, 512, 0, 1);
    // v from src (no pos)
    k_gemm_bf16<<<dim3(64, 2), 256, 0, stream>>>(srcb, 256, wqkv_l + 512 * 256, 256, ipb_l + 512,
                                                 nullptr, vb, 256, 8192, 256, 256, 0, 1);
    k_attn<<<dim3(8192), 256, 0, stream>>>(qkb, vb, ctx);
    k_gemm_bf16<<<dim3(64, 2), 256, 0, stream>>>(ctx, 256, outw_l, 256, outb_l,
                                                 tmp, nullptr, 256, 8192, 256, 256, 0, 0);
    k_add_ln<<<dim3(8192), 256, 0, stream>>>(src, srcb, tmp, g1_l, b1_l);
    k_gemm_bf16<<<dim3(64, 9), 256, 0, stream>>>(srcb, 256, l1w_l, 256, l1b_l,
                                                 nullptr, ff, 1152, 8192, 256, 1152, 1, 1);
    k_gemm_bf16<<<dim3(64, 2), 256, 0, stream>>>(ff, 1152, l2w_l, 1152, l2b_l,
                                                 tmp, nullptr, 256, 8192, 1152, 256, 0, 0);
    k_add_ln<<<dim3(8192), 256, 0, stream>>>(src, srcb, tmp, g2_l, b2_l);
  }

  // ---- output ----
  k_nxc_to_cxn<<<dim3(8, 32, 8), dim3(32, 32), 0, stream>>>(src, (float*)d_out);
}

// Round 3
// 1847.990 us; speedup vs baseline: 2.3971x; 1.4357x over previous
//
#include <hip/hip_runtime.h>
#include <hip/hip_bf16.h>

// B=8, C=256, NH=8, DH=32, N=1024 (32x32), L=8, DFF=1025 (pad 1152)
// conv0: im2col (Ci=3) + MFMA GEMM. convs 1-7: implicit-GEMM (gather A-stage).
// Transformer: bf16 MFMA GEMMs (BM=64), pos folded into QKV epilogue,
// fp32 residual/LN, exact-sparse 7x7 attention.

typedef __bf16 bf16x8 __attribute__((ext_vector_type(8)));
typedef float f32x4 __attribute__((ext_vector_type(4)));

__device__ __forceinline__ unsigned short f2bf(float f) {
  unsigned int u = __float_as_uint(f);
  unsigned int r = (u + 0x7fffu + ((u >> 16) & 1u)) >> 16;
  return (unsigned short)r;
}
__device__ __forceinline__ float bf2f(unsigned short h) {
  return __uint_as_float(((unsigned int)h) << 16);
}

#define GLD16(src, dst)                                                        \
  __builtin_amdgcn_global_load_lds(                                            \
      (const __attribute__((address_space(1))) unsigned int*)(src),            \
      (__attribute__((address_space(3))) unsigned int*)(dst), 16, 0, 0)

// ---------------- unified bf16 MFMA GEMM ----------------
// C[M,Npad] = A[M,K] @ B[Npad,K]^T (+bias +posadd, act), BN=128, BK=32.
// MODE 0: A linear [M][lda]. MODE 1: implicit conv gather from NHWC xin=A
//   (Ci%32==0, Hi==Wi, Wo = Hi/stride = 1<<lw, K = 9*Ci, M = Bz*Wo*Wo).
// act: 0 none, 1 relu, 2 silu. omode: 0 f32, 1 bf16, 2 both.
template<int BM, int MODE>
__global__ __launch_bounds__(256) void k_gemm(
    const unsigned short* __restrict__ A, int lda,
    const unsigned short* __restrict__ Bw, int ldb,
    const float* __restrict__ bias, const float* __restrict__ posadd,
    float* __restrict__ C, unsigned short* __restrict__ Cb, int ldc,
    int K, int Nstore, int act, int omode, long long zsB, long long zsC,
    const unsigned short* __restrict__ zpage, int Ci, int Hi, int stride, int lw)
{
  constexpr int ACH = BM / 64;     // A-chunk loads per thread
  constexpr int MF  = BM / 32;     // m fragments per wave
  __shared__ unsigned short lA[2][BM * 32];
  __shared__ unsigned short lB[2][128 * 32];
  int tid = threadIdx.x, lane = tid & 63, wid = tid >> 6;
  int bm = blockIdx.x * BM, bn = blockIdx.y << 7;
  const unsigned short* Bz = Bw + (size_t)blockIdx.z * zsB;
  int crow = lane >> 2, ckof = (lane & 3) << 3;
  const unsigned short* Bbase = Bz + (size_t)bn * ldb + ckof;
  const unsigned short* Abase = A + (size_t)bm * lda + ckof;

  int hb[ACH], wb[ACH];
  size_t ab[ACH];
  int dh = 0, dw = 0, cc = 0;
  if (MODE == 1) {
#pragma unroll
    for (int i = 0; i < ACH; ++i) {
      int c = (ACH == 2) ? wid * 2 + i : wid;
      int pos = bm + c * 16 + crow;
      int b = pos >> (2 * lw);
      int rem = pos & ((1 << (2 * lw)) - 1);
      int ho = rem >> lw, wo = rem & ((1 << lw) - 1);
      hb[i] = ho * stride - 1;
      wb[i] = wo * stride - 1;
      ab[i] = ((size_t)b * Hi * Hi) * Ci + ckof;
    }
  }

  auto stage = [&](int buf, int k0s) {
#pragma unroll
    for (int i = 0; i < ACH; ++i) {
      int c = (ACH == 2) ? wid * 2 + i : wid;
      if constexpr (MODE == 0) {
        int row = c * 16 + crow;
        GLD16(Abase + (size_t)row * lda + k0s, &lA[buf][c * 512]);
      } else {
        int hi = hb[i] + dh, wi = wb[i] + dw;
        const unsigned short* ap =
            ((unsigned)hi < (unsigned)Hi && (unsigned)wi < (unsigned)Hi)
                ? (A + ab[i] + ((size_t)hi * Hi + wi) * Ci + cc)
                : zpage;
        GLD16(ap, &lA[buf][c * 512]);
      }
    }
#pragma unroll
    for (int i = 0; i < 2; ++i) {
      int c = wid * 2 + i;
      int row = c * 16 + crow;
      GLD16(Bbase + (size_t)row * ldb + k0s, &lB[buf][c * 512]);
    }
  };
  auto adv = [&]() {
    if (MODE == 1) {
      cc += 32;
      if (cc >= Ci) { cc = 0; if (++dw == 3) { dw = 0; ++dh; } }
    }
  };

  f32x4 acc[MF][4];
#pragma unroll
  for (int m = 0; m < MF; ++m)
#pragma unroll
    for (int n = 0; n < 4; ++n)
#pragma unroll
      for (int j = 0; j < 4; ++j) acc[m][n][j] = 0.f;

  stage(0, 0);
  adv();
  int wm = wid >> 1, wn = wid & 1;
  int r0 = wm * (BM / 2) + (lane & 15);
  int c0 = wn * 64 + (lane & 15);
  int kq = (lane >> 4) << 3;
  int nkt = K >> 5, cur = 0;
  for (int kt = 0; kt < nkt; ++kt) {
    __syncthreads();
    if (kt + 1 < nkt) { stage(cur ^ 1, (kt + 1) << 5); adv(); }
    bf16x8 afr[MF], bfr[4];
#pragma unroll
    for (int m = 0; m < MF; ++m)
      afr[m] = *(const bf16x8*)&lA[cur][(r0 + m * 16) * 32 + kq];
#pragma unroll
    for (int n = 0; n < 4; ++n)
      bfr[n] = *(const bf16x8*)&lB[cur][(c0 + n * 16) * 32 + kq];
#pragma unroll
    for (int m = 0; m < MF; ++m)
#pragma unroll
      for (int n = 0; n < 4; ++n)
        acc[m][n] = __builtin_amdgcn_mfma_f32_16x16x32_bf16(afr[m], bfr[n], acc[m][n], 0, 0, 0);
    cur ^= 1;
  }

  float* Cz = C ? C + (size_t)blockIdx.z * zsC : nullptr;
  unsigned short* Cbz = Cb ? Cb + (size_t)blockIdx.z * zsC : nullptr;
  int colb = bn + wn * 64 + (lane & 15);
  int rowb = bm + wm * (BM / 2) + ((lane >> 4) << 2);
#pragma unroll
  for (int n = 0; n < 4; ++n) {
    int col = colb + n * 16;
    if (col >= Nstore) continue;
    float bs = bias ? bias[col] : 0.f;
#pragma unroll
    for (int m = 0; m < MF; ++m) {
#pragma unroll
      for (int j = 0; j < 4; ++j) {
        int row = rowb + m * 16 + j;
        float v = acc[m][n][j] + bs;
        if (posadd && col < 512) v += posadd[((row & 1023) << 9) + col];
        if (act == 1) v = fmaxf(v, 0.f);
        else if (act == 2) v = v / (1.f + __expf(-v));
        size_t off = (size_t)row * ldc + col;
        if (omode == 0) Cz[off] = v;
        else if (omode == 1) Cbz[off] = f2bf(v);
        else { Cz[off] = v; Cbz[off] = f2bf(v); }
      }
    }
  }
}

// ---------------- conv0 im2col: NCHW f32 hint -> [rows][32] bf16 ----------------
__global__ __launch_bounds__(256) void k_im2col0(
    const float* __restrict__ x, unsigned short* __restrict__ dst, int row0, int total)
{
  for (int idx = blockIdx.x * 256 + threadIdx.x; idx < total; idx += gridDim.x * 256) {
    int r = idx >> 5, e = idx & 31;
    int pos = row0 + r;
    int b = pos >> 16, rem = pos & 65535, ho = rem >> 8, wo = rem & 255;
    unsigned short val = 0;
    if (e < 27) {
      int t9 = e / 3, ci = e - t9 * 3;
      int hi = ho + (t9 / 3) - 1, wi = wo + (t9 - (t9 / 3) * 3) - 1;
      if ((unsigned)hi < 256u && (unsigned)wi < 256u)
        val = f2bf(x[(((size_t)b * 3 + ci) << 16) + (hi << 8) + wi]);
    }
    dst[idx] = val;
  }
}

// ---------------- conv weight permute: OIHW f32 -> [CoP][t*CiP+ci] bf16 ----------
__global__ __launch_bounds__(256) void k_wperm(
    const float* __restrict__ w, unsigned short* __restrict__ wp,
    int Co, int CiR, int CiP, int CoP, int Kpad)
{
  int idx = blockIdx.x * 256 + threadIdx.x;
  if (idx >= CoP * Kpad) return;
  int co = idx / Kpad, k = idx - co * Kpad;
  int t = k / CiP, ci = k - t * CiP;
  float v = 0.f;
  if (co < Co && t < 9 && ci < CiR) v = w[((size_t)co * CiR + ci) * 9 + t];
  wp[idx] = f2bf(v);
}

// ---------------- pad-convert fp32 -> bf16 / padded fp32, per layer slab --------
__global__ void k_cvt_pad(const float* __restrict__ in, unsigned short* __restrict__ outb,
                          float* __restrict__ outf, int R, int C, int Rp, int Cp)
{
  int l = blockIdx.y;
  int total = Rp * Cp;
  for (int idx = blockIdx.x * 256 + threadIdx.x; idx < total; idx += gridDim.x * 256) {
    int r = idx / Cp, c = idx - r * Cp;
    float v = (r < R && c < C) ? in[((size_t)l * R + r) * C + c] : 0.f;
    size_t o = (size_t)l * total + idx;
    if (outb) outb[o] = f2bf(v);
    if (outf) outf[o] = v;
  }
}

// ---------------- sine positional embedding (1024, 256) -> bf16 ----------------
__global__ __launch_bounds__(256) void k_pos(unsigned short* __restrict__ posb)
{
  int n = blockIdx.x, c = threadIdx.x;
  int ih = n >> 5, iw = n & 31;
  float coord = (c < 128) ? (float)(ih + 1) : (float)(iw + 1);
  int cc = c & 127;
  float e = (float)((cc >> 1) << 1) * (1.f / 128.f);
  float t = coord / powf(10000.f, e);
  posb[(n << 8) + c] = f2bf((cc & 1) ? cosf(t) : sinf(t));
}

// ---------------- neighborhood attention (7x7), qkv packed stride 768 ----------
__global__ __launch_bounds__(256) void k_attn(
    const unsigned short* __restrict__ qkv, unsigned short* __restrict__ ctx)
{
  int bn = blockIdx.x;
  int b = bn >> 10, n = bn & 1023;
  int ih = n >> 5, iw = n & 31;
  int g = threadIdx.x >> 5;   // head
  int l = threadIdx.x & 31;   // dim
  const float scale = 0.17677669529663687f;  // 1/sqrt(32)
  float qd = bf2f(qkv[(size_t)bn * 768 + (g << 5) + l]) * scale;
  float m_run = -1e30f, l_run = 0.f, acc = 0.f;
  int h0 = max(ih - 3, 0), h1 = min(ih + 3, 31);
  int w0 = max(iw - 3, 0), w1 = min(iw + 3, 31);
  for (int mh = h0; mh <= h1; ++mh) {
    for (int mw = w0; mw <= w1; ++mw) {
      size_t mpos = (size_t)((b << 10) + (mh << 5) + mw) * 768;
      float s = qd * bf2f(qkv[mpos + 256 + (g << 5) + l]);
      s += __shfl_xor(s, 1); s += __shfl_xor(s, 2); s += __shfl_xor(s, 4);
      s += __shfl_xor(s, 8); s += __shfl_xor(s, 16);
      float mn = fmaxf(m_run, s);
      float p = __expf(s - mn);
      float corr = __expf(m_run - mn);
      l_run = l_run * corr + p;
      acc = acc * corr + p * bf2f(qkv[mpos + 512 + (g << 5) + l]);
      m_run = mn;
    }
  }
  ctx[((size_t)bn << 8) + (g << 5) + l] = f2bf(acc / l_run);
}

// ---------------- fused residual add + LayerNorm -> src (f32) + srcb (bf16) ----
__global__ __launch_bounds__(256) void k_add_ln(
    float* __restrict__ s, unsigned short* __restrict__ sb, const float* __restrict__ d,
    const float* __restrict__ g, const float* __restrict__ b)
{
  int row = blockIdx.x, c = threadIdx.x;
  size_t idx = ((size_t)row << 8) + c;
  float x = s[idx] + d[idx];
  __shared__ float red[4];
  float t = x;
  t += __shfl_xor(t, 1); t += __shfl_xor(t, 2); t += __shfl_xor(t, 4);
  t += __shfl_xor(t, 8); t += __shfl_xor(t, 16); t += __shfl_xor(t, 32);
  if ((c & 63) == 0) red[c >> 6] = t;
  __syncthreads();
  float mu = (red[0] + red[1] + red[2] + red[3]) * (1.f / 256.f);
  float dx = x - mu;
  float u = dx * dx;
  __syncthreads();
  u += __shfl_xor(u, 1); u += __shfl_xor(u, 2); u += __shfl_xor(u, 4);
  u += __shfl_xor(u, 8); u += __shfl_xor(u, 16); u += __shfl_xor(u, 32);
  if ((c & 63) == 0) red[c >> 6] = u;
  __syncthreads();
  float var = (red[0] + red[1] + red[2] + red[3]) * (1.f / 256.f);
  float r = rsqrtf(var + 1e-5f);
  float o = dx * r * g[c] + b[c];
  s[idx] = o;
  sb[idx] = f2bf(o);
}

// ---------------- (B,1024,256) f32 -> (B,256,32,32) ----------------
__global__ void k_nxc_to_cxn(const float* __restrict__ x, float* __restrict__ y)
{
  __shared__ float t[32][33];
  int b = blockIdx.z;
  int c0 = blockIdx.x * 32, n0 = blockIdx.y * 32;
  int tx = threadIdx.x, ty = threadIdx.y;
  t[ty][tx] = x[((size_t)(b * 1024 + n0 + ty)) * 256 + c0 + tx];
  __syncthreads();
  y[((size_t)(b * 256 + c0 + ty)) * 1024 + n0 + tx] = t[tx][ty];
}

extern "C" void kernel_launch(void* const* d_in, const int* in_sizes, int n_in,
                              void* d_out, int out_size, void* d_ws, size_t ws_size,
                              hipStream_t stream)
{
  const float* hint = (const float*)d_in[0];
  const float* cw[8];
  for (int i = 0; i < 8; ++i) cw[i] = (const float*)d_in[1 + i];
  const float* ipw  = (const float*)d_in[9];
  const float* ipb  = (const float*)d_in[10];
  const float* outw = (const float*)d_in[11];
  const float* outb = (const float*)d_in[12];
  const float* l1w  = (const float*)d_in[13];
  const float* l1b  = (const float*)d_in[14];
  const float* l2w  = (const float*)d_in[15];
  const float* l2b  = (const float*)d_in[16];
  const float* g1   = (const float*)d_in[17];
  const float* b1   = (const float*)d_in[18];
  const float* g2   = (const float*)d_in[19];
  const float* b2   = (const float*)d_in[20];

  float* ws = (float*)d_ws;
  size_t off = 0;
  float* bufA = ws + off; off += 8388608;   // NHWC ping / qkvb+ctx
  float* bufB = ws + off; off += 8388608;   // NHWC pong / tmp+ff
  float* imb  = ws + off; off += 2097152;   // conv0 im2col chunk (131072 x 32 bf16)
  float* src  = ws + off; off += 2097152;   // (8192, 256) f32
  unsigned short* srcb = (unsigned short*)(ws + off); off += 1048576;
  unsigned short* posb = (unsigned short*)(ws + off); off += 131072;   // (1024,256)
  float* posqk = ws + off; off += 4194304;  // 8 x 1024 x 512 f32
  unsigned short* wqkvb = (unsigned short*)(ws + off); off += 786432;  // 8x768x256
  unsigned short* outwb = (unsigned short*)(ws + off); off += 262144;  // 8x256x256
  unsigned short* l1wb  = (unsigned short*)(ws + off); off += 1179648; // 8x1152x256
  unsigned short* l2wb  = (unsigned short*)(ws + off); off += 1179648; // 8x256x1152
  float* l1bp = ws + off; off += 9216;      // 8x1152
  unsigned short* cwp[8];
  const int CoPs[8]  = {128, 128, 128, 128, 128, 128, 256, 256};
  const int CiRs[8]  = {3, 16, 16, 32, 32, 96, 96, 256};
  const int CiPs[8]  = {3, 32, 32, 32, 32, 96, 96, 256};
  const int Kpads[8] = {32, 288, 288, 288, 288, 864, 864, 2304};
  const int Cos[8]   = {16, 16, 32, 32, 96, 96, 256, 256};
  for (int i = 0; i < 8; ++i) { cwp[i] = (unsigned short*)(ws + off); off += (size_t)CoPs[i] * Kpads[i] / 2; }
  unsigned short* zpage = (unsigned short*)(ws + off); off += 64;

  hipMemsetAsync(zpage, 0, 256, stream);

  // ---- weight prep ----
  k_cvt_pad<<<dim3(768, 8), 256, 0, stream>>>(ipw,  wqkvb, nullptr, 768, 256, 768, 256);
  k_cvt_pad<<<dim3(256, 8), 256, 0, stream>>>(outw, outwb, nullptr, 256, 256, 256, 256);
  k_cvt_pad<<<dim3(1152, 8), 256, 0, stream>>>(l1w, l1wb, nullptr, 1025, 256, 1152, 256);
  k_cvt_pad<<<dim3(1152, 8), 256, 0, stream>>>(l2w, l2wb, nullptr, 256, 1025, 256, 1152);
  k_cvt_pad<<<dim3(5, 8), 256, 0, stream>>>(l1b, nullptr, l1bp, 1025, 1, 1152, 1);
  for (int i = 0; i < 8; ++i)
    k_wperm<<<(CoPs[i] * Kpads[i] + 255) / 256, 256, 0, stream>>>(
        cw[i], cwp[i], Cos[i], CiRs[i], CiPs[i], CoPs[i], Kpads[i]);
  k_pos<<<dim3(1024), 256, 0, stream>>>(posb);

  unsigned short* bufAu = (unsigned short*)bufA;
  unsigned short* bufBu = (unsigned short*)bufB;
  unsigned short* imbu  = (unsigned short*)imb;

  // ---- conv0: im2col + GEMM, 4 chunks of 131072 rows -> bufA NHWC(32) ----
  for (int c = 0; c < 4; ++c) {
    k_im2col0<<<16384, 256, 0, stream>>>(hint, imbu, c * 131072, 131072 * 32);
    k_gemm<128, 0><<<dim3(1024, 1), 256, 0, stream>>>(
        imbu, 32, cwp[0], 32, nullptr, nullptr, nullptr,
        bufAu + (size_t)c * 131072 * 32, 32, 32, 32, 2, 1, 0, 0,
        nullptr, 0, 0, 0, 0);
  }
  // ---- convs 1-7: implicit GEMM ----
  // (xin, Ci, Hi, stride, lw(Wo), K, wp, out, ldc, Nstore, act, omode)
  k_gemm<128, 1><<<dim3(4096, 1), 256, 0, stream>>>(   // conv1: 256^2, s1
      bufAu, 0, cwp[1], 288, nullptr, nullptr, nullptr, bufBu, 32, 288, 32, 2, 1,
      0, 0, zpage, 32, 256, 1, 8);
  k_gemm<128, 1><<<dim3(1024, 1), 256, 0, stream>>>(   // conv2: ->128^2, s2
      bufBu, 0, cwp[2], 288, nullptr, nullptr, nullptr, bufAu, 32, 288, 32, 2, 1,
      0, 0, zpage, 32, 256, 2, 7);
  k_gemm<128, 1><<<dim3(1024, 1), 256, 0, stream>>>(   // conv3: 128^2, s1
      bufAu, 0, cwp[3], 288, nullptr, nullptr, nullptr, bufBu, 32, 288, 32, 2, 1,
      0, 0, zpage, 32, 128, 1, 7);
  k_gemm<128, 1><<<dim3(256, 1), 256, 0, stream>>>(    // conv4: ->64^2, s2, Co96
      bufBu, 0, cwp[4], 288, nullptr, nullptr, nullptr, bufAu, 96, 288, 96, 2, 1,
      0, 0, zpage, 32, 128, 2, 6);
  k_gemm<128, 1><<<dim3(256, 1), 256, 0, stream>>>(    // conv5: 64^2, s1
      bufAu, 0, cwp[5], 864, nullptr, nullptr, nullptr, bufBu, 96, 864, 96, 2, 1,
      0, 0, zpage, 96, 64, 1, 6);
  k_gemm<64, 1><<<dim3(128, 2), 256, 0, stream>>>(     // conv6: ->32^2, s2, Co256
      bufBu, 0, cwp[6], 864, nullptr, nullptr, nullptr, bufAu, 256, 864, 256, 2, 1,
      0, 0, zpage, 96, 64, 2, 5);
  k_gemm<64, 1><<<dim3(128, 2), 256, 0, stream>>>(     // conv7: 32^2, s1, no act
      bufAu, 0, cwp[7], 2304, nullptr, nullptr, src, srcb, 256, 2304, 256, 0, 2,
      0, 0, zpage, 256, 32, 1, 5);

  // ---- posqk[l] = pos @ [Wq;Wk]^T, batched over 8 layers ----
  k_gemm<64, 0><<<dim3(16, 4, 8), 256, 0, stream>>>(
      posb, 256, wqkvb, 256, nullptr, nullptr, posqk, nullptr, 512, 256, 512, 0, 0,
      196608LL, 524288LL, nullptr, 0, 0, 0, 0);

  // in-transformer overlays
  unsigned short* qkvb = bufAu;                                  // 8192 x 768 bf16
  unsigned short* ctx  = (unsigned short*)(bufA + 3145728);      // 8192 x 256 bf16
  float* tmp           = bufB;                                   // 8192 x 256 f32
  unsigned short* ff   = (unsigned short*)(bufB + 2097152);      // 8192 x 1152 bf16

  // ---- transformer layers ----
  for (int l = 0; l < 8; ++l) {
    const unsigned short* wqkv_l = wqkvb + (size_t)l * 768 * 256;
    const float* ipb_l  = ipb  + (size_t)l * 768;
    const unsigned short* outw_l = outwb + (size_t)l * 256 * 256;
    const float* outb_l = outb + (size_t)l * 256;
    const unsigned short* l1w_l = l1wb + (size_t)l * 1152 * 256;
    const float* l1b_l  = l1bp + (size_t)l * 1152;
    const unsigned short* l2w_l = l2wb + (size_t)l * 256 * 1152;
    const float* l2b_l  = l2b  + (size_t)l * 256;
    const float* posqk_l = posqk + (size_t)l * 524288;
    const float* g1_l = g1 + l * 256; const float* b1_l = b1 + l * 256;
    const float* g2_l = g2 + l * 256; const float* b2_l = b2 + l * 256;

    k_gemm<64, 0><<<dim3(128, 6), 256, 0, stream>>>(   // QKV, pos folded into q,k
        srcb, 256, wqkv_l, 256, ipb_l, posqk_l, nullptr, qkvb, 768, 256, 768, 0, 1,
        0, 0, nullptr, 0, 0, 0, 0);
    k_attn<<<dim3(8192), 256, 0, stream>>>(qkvb, ctx);
    k_gemm<64, 0><<<dim3(128, 2), 256, 0, stream>>>(   // out proj
        ctx, 256, outw_l, 256, outb_l, nullptr, tmp, nullptr, 256, 256, 256, 0, 0,
        0, 0, nullptr, 0, 0, 0, 0);
    k_add_ln<<<dim3(8192), 256, 0, stream>>>(src, srcb, tmp, g1_l, b1_l);
    k_gemm<64, 0><<<dim3(128, 9), 256, 0, stream>>>(   // lin1 + relu
        srcb, 256, l1w_l, 256, l1b_l, nullptr, nullptr, ff, 1152, 256, 1152, 1, 1,
        0, 0, nullptr, 0, 0, 0, 0);
    k_gemm<64, 0><<<dim3(128, 2), 256, 0, stream>>>(   // lin2
        ff, 1152, l2w_l, 1152, l2b_l, nullptr, tmp, nullptr, 256, 1152, 256, 0, 0,
        0, 0, nullptr, 0, 0, 0, 0);
    k_add_ln<<<dim3(8192), 256, 0, stream>>>(src, srcb, tmp, g2_l, b2_l);
  }

  // ---- output ----
  k_nxc_to_cxn<<<dim3(8, 32, 8), dim3(32, 32), 0, stream>>>(src, (float*)d_out);
}

// Round 4
// 1698.096 us; speedup vs baseline: 2.6088x; 1.0883x over previous
//
#include <hip/hip_runtime.h>
#include <hip/hip_bf16.h>

// B=8, C=256, NH=8, DH=32, N=1024 (32x32), L=8, DFF=1025 (pad 1152)
// conv0: im2col (Ci=3) + MFMA GEMM. convs 1-7: implicit-GEMM (gather A-stage).
// Transformer: bf16 MFMA GEMMs (BM=64), pos folded into QKV epilogue,
// fp32 residual/LN, exact-sparse 7x7 attention (2-phase: key-split QK, dim-split PV).

typedef __bf16 bf16x8 __attribute__((ext_vector_type(8)));
typedef float f32x4 __attribute__((ext_vector_type(4)));
typedef unsigned short us8v __attribute__((ext_vector_type(8)));

__device__ __forceinline__ unsigned short f2bf(float f) {
  unsigned int u = __float_as_uint(f);
  unsigned int r = (u + 0x7fffu + ((u >> 16) & 1u)) >> 16;
  return (unsigned short)r;
}
__device__ __forceinline__ float bf2f(unsigned short h) {
  return __uint_as_float(((unsigned int)h) << 16);
}

#define GLD16(src, dst)                                                        \
  __builtin_amdgcn_global_load_lds(                                            \
      (const __attribute__((address_space(1))) unsigned int*)(src),            \
      (__attribute__((address_space(3))) unsigned int*)(dst), 16, 0, 0)

// ---------------- unified bf16 MFMA GEMM ----------------
// C[M,Npad] = A[M,K] @ B[Npad,K]^T (+bias +posadd, act), BN=128, BK=32.
// MODE 0: A linear [M][lda]. MODE 1: implicit conv gather from NHWC xin=A
//   (Ci%32==0, Hi==Wi, Wo = Hi/stride = 1<<lw, K = 9*Ci, M = Bz*Wo*Wo).
// act: 0 none, 1 relu, 2 silu. omode: 0 f32, 1 bf16, 2 both.
template<int BM, int MODE>
__global__ __launch_bounds__(256) void k_gemm(
    const unsigned short* __restrict__ A, int lda,
    const unsigned short* __restrict__ Bw, int ldb,
    const float* __restrict__ bias, const float* __restrict__ posadd,
    float* __restrict__ C, unsigned short* __restrict__ Cb, int ldc,
    int K, int Nstore, int act, int omode, long long zsB, long long zsC,
    const unsigned short* __restrict__ zpage, int Ci, int Hi, int stride, int lw)
{
  constexpr int ACH = BM / 64;     // A-chunk loads per thread
  constexpr int MF  = BM / 32;     // m fragments per wave
  __shared__ unsigned short lA[2][BM * 32];
  __shared__ unsigned short lB[2][128 * 32];
  int tid = threadIdx.x, lane = tid & 63, wid = tid >> 6;
  int bm = blockIdx.x * BM, bn = blockIdx.y << 7;
  const unsigned short* Bz = Bw + (size_t)blockIdx.z * zsB;
  int crow = lane >> 2, ckof = (lane & 3) << 3;
  const unsigned short* Bbase = Bz + (size_t)bn * ldb + ckof;
  const unsigned short* Abase = A + (size_t)bm * lda + ckof;

  int hb[ACH], wb[ACH];
  size_t ab[ACH];
  int dh = 0, dw = 0, cc = 0;
  if (MODE == 1) {
#pragma unroll
    for (int i = 0; i < ACH; ++i) {
      int c = (ACH == 2) ? wid * 2 + i : wid;
      int pos = bm + c * 16 + crow;
      int b = pos >> (2 * lw);
      int rem = pos & ((1 << (2 * lw)) - 1);
      int ho = rem >> lw, wo = rem & ((1 << lw) - 1);
      hb[i] = ho * stride - 1;
      wb[i] = wo * stride - 1;
      ab[i] = ((size_t)b * Hi * Hi) * Ci + ckof;
    }
  }

  auto stage = [&](int buf, int k0s) {
#pragma unroll
    for (int i = 0; i < ACH; ++i) {
      int c = (ACH == 2) ? wid * 2 + i : wid;
      if constexpr (MODE == 0) {
        int row = c * 16 + crow;
        GLD16(Abase + (size_t)row * lda + k0s, &lA[buf][c * 512]);
      } else {
        int hi = hb[i] + dh, wi = wb[i] + dw;
        const unsigned short* ap =
            ((unsigned)hi < (unsigned)Hi && (unsigned)wi < (unsigned)Hi)
                ? (A + ab[i] + ((size_t)hi * Hi + wi) * Ci + cc)
                : zpage;
        GLD16(ap, &lA[buf][c * 512]);
      }
    }
#pragma unroll
    for (int i = 0; i < 2; ++i) {
      int c = wid * 2 + i;
      int row = c * 16 + crow;
      GLD16(Bbase + (size_t)row * ldb + k0s, &lB[buf][c * 512]);
    }
  };
  auto adv = [&]() {
    if (MODE == 1) {
      cc += 32;
      if (cc >= Ci) { cc = 0; if (++dw == 3) { dw = 0; ++dh; } }
    }
  };

  f32x4 acc[MF][4];
#pragma unroll
  for (int m = 0; m < MF; ++m)
#pragma unroll
    for (int n = 0; n < 4; ++n)
#pragma unroll
      for (int j = 0; j < 4; ++j) acc[m][n][j] = 0.f;

  stage(0, 0);
  adv();
  int wm = wid >> 1, wn = wid & 1;
  int r0 = wm * (BM / 2) + (lane & 15);
  int c0 = wn * 64 + (lane & 15);
  int kq = (lane >> 4) << 3;
  int nkt = K >> 5, cur = 0;
  for (int kt = 0; kt < nkt; ++kt) {
    __syncthreads();
    if (kt + 1 < nkt) { stage(cur ^ 1, (kt + 1) << 5); adv(); }
    bf16x8 afr[MF], bfr[4];
#pragma unroll
    for (int m = 0; m < MF; ++m)
      afr[m] = *(const bf16x8*)&lA[cur][(r0 + m * 16) * 32 + kq];
#pragma unroll
    for (int n = 0; n < 4; ++n)
      bfr[n] = *(const bf16x8*)&lB[cur][(c0 + n * 16) * 32 + kq];
#pragma unroll
    for (int m = 0; m < MF; ++m)
#pragma unroll
      for (int n = 0; n < 4; ++n)
        acc[m][n] = __builtin_amdgcn_mfma_f32_16x16x32_bf16(afr[m], bfr[n], acc[m][n], 0, 0, 0);
    cur ^= 1;
  }

  float* Cz = C ? C + (size_t)blockIdx.z * zsC : nullptr;
  unsigned short* Cbz = Cb ? Cb + (size_t)blockIdx.z * zsC : nullptr;
  int colb = bn + wn * 64 + (lane & 15);
  int rowb = bm + wm * (BM / 2) + ((lane >> 4) << 2);
#pragma unroll
  for (int n = 0; n < 4; ++n) {
    int col = colb + n * 16;
    if (col >= Nstore) continue;
    float bs = bias ? bias[col] : 0.f;
#pragma unroll
    for (int m = 0; m < MF; ++m) {
#pragma unroll
      for (int j = 0; j < 4; ++j) {
        int row = rowb + m * 16 + j;
        float v = acc[m][n][j] + bs;
        if (posadd && col < 512) v += posadd[((row & 1023) << 9) + col];
        if (act == 1) v = fmaxf(v, 0.f);
        else if (act == 2) v = v / (1.f + __expf(-v));
        size_t off = (size_t)row * ldc + col;
        if (omode == 0) Cz[off] = v;
        else if (omode == 1) Cbz[off] = f2bf(v);
        else { Cz[off] = v; Cbz[off] = f2bf(v); }
      }
    }
  }
}

// ---------------- conv0 im2col: NCHW f32 hint -> [rows][32] bf16 ----------------
__global__ __launch_bounds__(256) void k_im2col0(
    const float* __restrict__ x, unsigned short* __restrict__ dst, int row0, int total)
{
  for (int idx = blockIdx.x * 256 + threadIdx.x; idx < total; idx += gridDim.x * 256) {
    int r = idx >> 5, e = idx & 31;
    int pos = row0 + r;
    int b = pos >> 16, rem = pos & 65535, ho = rem >> 8, wo = rem & 255;
    unsigned short val = 0;
    if (e < 27) {
      int t9 = e / 3, ci = e - t9 * 3;
      int hi = ho + (t9 / 3) - 1, wi = wo + (t9 - (t9 / 3) * 3) - 1;
      if ((unsigned)hi < 256u && (unsigned)wi < 256u)
        val = f2bf(x[(((size_t)b * 3 + ci) << 16) + (hi << 8) + wi]);
    }
    dst[idx] = val;
  }
}

// ---------------- conv weight permute: OIHW f32 -> [CoP][t*CiP+ci] bf16 ----------
__global__ __launch_bounds__(256) void k_wperm(
    const float* __restrict__ w, unsigned short* __restrict__ wp,
    int Co, int CiR, int CiP, int CoP, int Kpad)
{
  int idx = blockIdx.x * 256 + threadIdx.x;
  if (idx >= CoP * Kpad) return;
  int co = idx / Kpad, k = idx - co * Kpad;
  int t = k / CiP, ci = k - t * CiP;
  float v = 0.f;
  if (co < Co && t < 9 && ci < CiR) v = w[((size_t)co * CiR + ci) * 9 + t];
  wp[idx] = f2bf(v);
}

// ---------------- pad-convert fp32 -> bf16 / padded fp32, per layer slab --------
__global__ void k_cvt_pad(const float* __restrict__ in, unsigned short* __restrict__ outb,
                          float* __restrict__ outf, int R, int C, int Rp, int Cp)
{
  int l = blockIdx.y;
  int total = Rp * Cp;
  for (int idx = blockIdx.x * 256 + threadIdx.x; idx < total; idx += gridDim.x * 256) {
    int r = idx / Cp, c = idx - r * Cp;
    float v = (r < R && c < C) ? in[((size_t)l * R + r) * C + c] : 0.f;
    size_t o = (size_t)l * total + idx;
    if (outb) outb[o] = f2bf(v);
    if (outf) outf[o] = v;
  }
}

// ---------------- sine positional embedding (1024, 256) -> bf16 ----------------
__global__ __launch_bounds__(256) void k_pos(unsigned short* __restrict__ posb)
{
  int n = blockIdx.x, c = threadIdx.x;
  int ih = n >> 5, iw = n & 31;
  float coord = (c < 128) ? (float)(ih + 1) : (float)(iw + 1);
  int cc = c & 127;
  float e = (float)((cc >> 1) << 1) * (1.f / 128.f);
  float t = coord / powf(10000.f, e);
  posb[(n << 8) + c] = f2bf((cc & 1) ? cosf(t) : sinf(t));
}

// ---------------- neighborhood attention (7x7), qkv packed stride 768 ----------
// Phase A: lane = key (slots l, l+32 of the 7x7 window), full dot in registers.
// Two-pass softmax (max-reduce, exp, sum-reduce) -> p in LDS (2KB).
// Phase B: lane = dim, 49 iters of {LDS broadcast p, coalesced v load, fma};
// out-of-grid keys skipped by scalar branch (ih,iw are SGPR).
__global__ __launch_bounds__(256) void k_attn(
    const unsigned short* __restrict__ qkv, unsigned short* __restrict__ ctx)
{
  __shared__ float lds_p[8][64];
  int bn = blockIdx.x;
  int b = bn >> 10, n = bn & 1023;
  int ih = n >> 5, iw = n & 31;
  int g = threadIdx.x >> 5;   // head
  int l = threadIdx.x & 31;   // lane within head
  const float scale = 0.17677669529663687f;  // 1/sqrt(32)

  // load q row (all lanes of head read same 64B -> broadcast), fold scale
  const unsigned short* qrow = qkv + (size_t)bn * 768 + (g << 5);
  float q[32];
#pragma unroll
  for (int i = 0; i < 4; ++i) {
    us8v u = *(const us8v*)(qrow + i * 8);
#pragma unroll
    for (int j = 0; j < 8; ++j) q[i * 8 + j] = bf2f(u[j]) * scale;
  }

  // phase A: scores for key slots kk = l, l+32
  float s[2];
#pragma unroll
  for (int ss = 0; ss < 2; ++ss) {
    int kk = l + ss * 32;
    int d7 = kk / 7, r7 = kk - d7 * 7;
    int mh = ih - 3 + d7, mw = iw - 3 + r7;
    bool valid = (kk < 49) && ((unsigned)mh < 32u) && ((unsigned)mw < 32u);
    int mpos = valid ? ((b << 10) + (mh << 5) + mw) : bn;
    const unsigned short* krow = qkv + (size_t)mpos * 768 + 256 + (g << 5);
    float dot = 0.f;
#pragma unroll
    for (int i = 0; i < 4; ++i) {
      us8v u = *(const us8v*)(krow + i * 8);
#pragma unroll
      for (int j = 0; j < 8; ++j) dot = fmaf(q[i * 8 + j], bf2f(u[j]), dot);
    }
    s[ss] = valid ? dot : -1e30f;
  }
  // max over the 32-lane head group (masks <=16 stay within the group)
  float m = fmaxf(s[0], s[1]);
  m = fmaxf(m, __shfl_xor(m, 1)); m = fmaxf(m, __shfl_xor(m, 2));
  m = fmaxf(m, __shfl_xor(m, 4)); m = fmaxf(m, __shfl_xor(m, 8));
  m = fmaxf(m, __shfl_xor(m, 16));
  float p0 = __expf(s[0] - m), p1 = __expf(s[1] - m);
  float t = p0 + p1;
  t += __shfl_xor(t, 1); t += __shfl_xor(t, 2); t += __shfl_xor(t, 4);
  t += __shfl_xor(t, 8); t += __shfl_xor(t, 16);
  float inv = 1.f / t;
  lds_p[g][l] = p0;
  lds_p[g][l + 32] = p1;   // same-wave write/read: compiler's lgkmcnt suffices

  // phase B: lane = dim l, accumulate over valid keys
  float acc = 0.f;
  const unsigned short* vbase = qkv + 512 + (g << 5) + l;
#pragma unroll
  for (int kk = 0; kk < 49; ++kk) {
    int mh = ih - 3 + kk / 7, mw = iw - 3 + kk % 7;   // scalar (SGPR) per kk
    if ((unsigned)mh < 32u && (unsigned)mw < 32u) {
      int mpos = (b << 10) + (mh << 5) + mw;
      acc = fmaf(lds_p[g][kk], bf2f(vbase[(size_t)mpos * 768]), acc);
    }
  }
  ctx[((size_t)bn << 8) + (g << 5) + l] = f2bf(acc * inv);
}

// ---------------- fused residual add + LayerNorm -> src (f32) + srcb (bf16) ----
__global__ __launch_bounds__(256) void k_add_ln(
    float* __restrict__ s, unsigned short* __restrict__ sb, const float* __restrict__ d,
    const float* __restrict__ g, const float* __restrict__ b)
{
  int row = blockIdx.x, c = threadIdx.x;
  size_t idx = ((size_t)row << 8) + c;
  float x = s[idx] + d[idx];
  __shared__ float red[4];
  float t = x;
  t += __shfl_xor(t, 1); t += __shfl_xor(t, 2); t += __shfl_xor(t, 4);
  t += __shfl_xor(t, 8); t += __shfl_xor(t, 16); t += __shfl_xor(t, 32);
  if ((c & 63) == 0) red[c >> 6] = t;
  __syncthreads();
  float mu = (red[0] + red[1] + red[2] + red[3]) * (1.f / 256.f);
  float dx = x - mu;
  float u = dx * dx;
  __syncthreads();
  u += __shfl_xor(u, 1); u += __shfl_xor(u, 2); u += __shfl_xor(u, 4);
  u += __shfl_xor(u, 8); u += __shfl_xor(u, 16); u += __shfl_xor(u, 32);
  if ((c & 63) == 0) red[c >> 6] = u;
  __syncthreads();
  float var = (red[0] + red[1] + red[2] + red[3]) * (1.f / 256.f);
  float r = rsqrtf(var + 1e-5f);
  float o = dx * r * g[c] + b[c];
  s[idx] = o;
  sb[idx] = f2bf(o);
}

// ---------------- (B,1024,256) f32 -> (B,256,32,32) ----------------
__global__ void k_nxc_to_cxn(const float* __restrict__ x, float* __restrict__ y)
{
  __shared__ float t[32][33];
  int b = blockIdx.z;
  int c0 = blockIdx.x * 32, n0 = blockIdx.y * 32;
  int tx = threadIdx.x, ty = threadIdx.y;
  t[ty][tx] = x[((size_t)(b * 1024 + n0 + ty)) * 256 + c0 + tx];
  __syncthreads();
  y[((size_t)(b * 256 + c0 + ty)) * 1024 + n0 + tx] = t[tx][ty];
}

extern "C" void kernel_launch(void* const* d_in, const int* in_sizes, int n_in,
                              void* d_out, int out_size, void* d_ws, size_t ws_size,
                              hipStream_t stream)
{
  const float* hint = (const float*)d_in[0];
  const float* cw[8];
  for (int i = 0; i < 8; ++i) cw[i] = (const float*)d_in[1 + i];
  const float* ipw  = (const float*)d_in[9];
  const float* ipb  = (const float*)d_in[10];
  const float* outw = (const float*)d_in[11];
  const float* outb = (const float*)d_in[12];
  const float* l1w  = (const float*)d_in[13];
  const float* l1b  = (const float*)d_in[14];
  const float* l2w  = (const float*)d_in[15];
  const float* l2b  = (const float*)d_in[16];
  const float* g1   = (const float*)d_in[17];
  const float* b1   = (const float*)d_in[18];
  const float* g2   = (const float*)d_in[19];
  const float* b2   = (const float*)d_in[20];

  float* ws = (float*)d_ws;
  size_t off = 0;
  float* bufA = ws + off; off += 8388608;   // NHWC ping / qkvb+ctx
  float* bufB = ws + off; off += 8388608;   // NHWC pong / tmp+ff
  float* imb  = ws + off; off += 2097152;   // conv0 im2col chunk (131072 x 32 bf16)
  float* src  = ws + off; off += 2097152;   // (8192, 256) f32
  unsigned short* srcb = (unsigned short*)(ws + off); off += 1048576;
  unsigned short* posb = (unsigned short*)(ws + off); off += 131072;   // (1024,256)
  float* posqk = ws + off; off += 4194304;  // 8 x 1024 x 512 f32
  unsigned short* wqkvb = (unsigned short*)(ws + off); off += 786432;  // 8x768x256
  unsigned short* outwb = (unsigned short*)(ws + off); off += 262144;  // 8x256x256
  unsigned short* l1wb  = (unsigned short*)(ws + off); off += 1179648; // 8x1152x256
  unsigned short* l2wb  = (unsigned short*)(ws + off); off += 1179648; // 8x256x1152
  float* l1bp = ws + off; off += 9216;      // 8x1152
  unsigned short* cwp[8];
  const int CoPs[8]  = {128, 128, 128, 128, 128, 128, 256, 256};
  const int CiRs[8]  = {3, 16, 16, 32, 32, 96, 96, 256};
  const int CiPs[8]  = {3, 32, 32, 32, 32, 96, 96, 256};
  const int Kpads[8] = {32, 288, 288, 288, 288, 864, 864, 2304};
  const int Cos[8]   = {16, 16, 32, 32, 96, 96, 256, 256};
  for (int i = 0; i < 8; ++i) { cwp[i] = (unsigned short*)(ws + off); off += (size_t)CoPs[i] * Kpads[i] / 2; }
  unsigned short* zpage = (unsigned short*)(ws + off); off += 64;

  hipMemsetAsync(zpage, 0, 256, stream);

  // ---- weight prep ----
  k_cvt_pad<<<dim3(768, 8), 256, 0, stream>>>(ipw,  wqkvb, nullptr, 768, 256, 768, 256);
  k_cvt_pad<<<dim3(256, 8), 256, 0, stream>>>(outw, outwb, nullptr, 256, 256, 256, 256);
  k_cvt_pad<<<dim3(1152, 8), 256, 0, stream>>>(l1w, l1wb, nullptr, 1025, 256, 1152, 256);
  k_cvt_pad<<<dim3(1152, 8), 256, 0, stream>>>(l2w, l2wb, nullptr, 256, 1025, 256, 1152);
  k_cvt_pad<<<dim3(5, 8), 256, 0, stream>>>(l1b, nullptr, l1bp, 1025, 1, 1152, 1);
  for (int i = 0; i < 8; ++i)
    k_wperm<<<(CoPs[i] * Kpads[i] + 255) / 256, 256, 0, stream>>>(
        cw[i], cwp[i], Cos[i], CiRs[i], CiPs[i], CoPs[i], Kpads[i]);
  k_pos<<<dim3(1024), 256, 0, stream>>>(posb);

  unsigned short* bufAu = (unsigned short*)bufA;
  unsigned short* bufBu = (unsigned short*)bufB;
  unsigned short* imbu  = (unsigned short*)imb;

  // ---- conv0: im2col + GEMM, 4 chunks of 131072 rows -> bufA NHWC(32) ----
  for (int c = 0; c < 4; ++c) {
    k_im2col0<<<16384, 256, 0, stream>>>(hint, imbu, c * 131072, 131072 * 32);
    k_gemm<128, 0><<<dim3(1024, 1), 256, 0, stream>>>(
        imbu, 32, cwp[0], 32, nullptr, nullptr, nullptr,
        bufAu + (size_t)c * 131072 * 32, 32, 32, 32, 2, 1, 0, 0,
        nullptr, 0, 0, 0, 0);
  }
  // ---- convs 1-7: implicit GEMM ----
  k_gemm<128, 1><<<dim3(4096, 1), 256, 0, stream>>>(   // conv1: 256^2, s1
      bufAu, 0, cwp[1], 288, nullptr, nullptr, nullptr, bufBu, 32, 288, 32, 2, 1,
      0, 0, zpage, 32, 256, 1, 8);
  k_gemm<128, 1><<<dim3(1024, 1), 256, 0, stream>>>(   // conv2: ->128^2, s2
      bufBu, 0, cwp[2], 288, nullptr, nullptr, nullptr, bufAu, 32, 288, 32, 2, 1,
      0, 0, zpage, 32, 256, 2, 7);
  k_gemm<128, 1><<<dim3(1024, 1), 256, 0, stream>>>(   // conv3: 128^2, s1
      bufAu, 0, cwp[3], 288, nullptr, nullptr, nullptr, bufBu, 32, 288, 32, 2, 1,
      0, 0, zpage, 32, 128, 1, 7);
  k_gemm<128, 1><<<dim3(256, 1), 256, 0, stream>>>(    // conv4: ->64^2, s2, Co96
      bufBu, 0, cwp[4], 288, nullptr, nullptr, nullptr, bufAu, 96, 288, 96, 2, 1,
      0, 0, zpage, 32, 128, 2, 6);
  k_gemm<128, 1><<<dim3(256, 1), 256, 0, stream>>>(    // conv5: 64^2, s1
      bufAu, 0, cwp[5], 864, nullptr, nullptr, nullptr, bufBu, 96, 864, 96, 2, 1,
      0, 0, zpage, 96, 64, 1, 6);
  k_gemm<64, 1><<<dim3(128, 2), 256, 0, stream>>>(     // conv6: ->32^2, s2, Co256
      bufBu, 0, cwp[6], 864, nullptr, nullptr, nullptr, bufAu, 256, 864, 256, 2, 1,
      0, 0, zpage, 96, 64, 2, 5);
  k_gemm<64, 1><<<dim3(128, 2), 256, 0, stream>>>(     // conv7: 32^2, s1, no act
      bufAu, 0, cwp[7], 2304, nullptr, nullptr, src, srcb, 256, 2304, 256, 0, 2,
      0, 0, zpage, 256, 32, 1, 5);

  // ---- posqk[l] = pos @ [Wq;Wk]^T, batched over 8 layers ----
  k_gemm<64, 0><<<dim3(16, 4, 8), 256, 0, stream>>>(
      posb, 256, wqkvb, 256, nullptr, nullptr, posqk, nullptr, 512, 256, 512, 0, 0,
      196608LL, 524288LL, nullptr, 0, 0, 0, 0);

  // in-transformer overlays
  unsigned short* qkvb = bufAu;                                  // 8192 x 768 bf16
  unsigned short* ctx  = (unsigned short*)(bufA + 3145728);      // 8192 x 256 bf16
  float* tmp           = bufB;                                   // 8192 x 256 f32
  unsigned short* ff   = (unsigned short*)(bufB + 2097152);      // 8192 x 1152 bf16

  // ---- transformer layers ----
  for (int l = 0; l < 8; ++l) {
    const unsigned short* wqkv_l = wqkvb + (size_t)l * 768 * 256;
    const float* ipb_l  = ipb  + (size_t)l * 768;
    const unsigned short* outw_l = outwb + (size_t)l * 256 * 256;
    const float* outb_l = outb + (size_t)l * 256;
    const unsigned short* l1w_l = l1wb + (size_t)l * 1152 * 256;
    const float* l1b_l  = l1bp + (size_t)l * 1152;
    const unsigned short* l2w_l = l2wb + (size_t)l * 256 * 1152;
    const float* l2b_l  = l2b  + (size_t)l * 256;
    const float* posqk_l = posqk + (size_t)l * 524288;
    const float* g1_l = g1 + l * 256; const float* b1_l = b1 + l * 256;
    const float* g2_l = g2 + l * 256; const float* b2_l = b2 + l * 256;

    k_gemm<64, 0><<<dim3(128, 6), 256, 0, stream>>>(   // QKV, pos folded into q,k
        srcb, 256, wqkv_l, 256, ipb_l, posqk_l, nullptr, qkvb, 768, 256, 768, 0, 1,
        0, 0, nullptr, 0, 0, 0, 0);
    k_attn<<<dim3(8192), 256, 0, stream>>>(qkvb, ctx);
    k_gemm<64, 0><<<dim3(128, 2), 256, 0, stream>>>(   // out proj
        ctx, 256, outw_l, 256, outb_l, nullptr, tmp, nullptr, 256, 256, 256, 0, 0,
        0, 0, nullptr, 0, 0, 0, 0);
    k_add_ln<<<dim3(8192), 256, 0, stream>>>(src, srcb, tmp, g1_l, b1_l);
    k_gemm<64, 0><<<dim3(128, 9), 256, 0, stream>>>(   // lin1 + relu
        srcb, 256, l1w_l, 256, l1b_l, nullptr, nullptr, ff, 1152, 256, 1152, 1, 1,
        0, 0, nullptr, 0, 0, 0, 0);
    k_gemm<64, 0><<<dim3(128, 2), 256, 0, stream>>>(   // lin2
        ff, 1152, l2w_l, 1152, l2b_l, nullptr, tmp, nullptr, 256, 1152, 256, 0, 0,
        0, 0, nullptr, 0, 0, 0, 0);
    k_add_ln<<<dim3(8192), 256, 0, stream>>>(src, srcb, tmp, g2_l, b2_l);
  }

  // ---- output ----
  k_nxc_to_cxn<<<dim3(8, 32, 8), dim3(32, 32), 0, stream>>>(src, (float*)d_out);
}

// Round 5
// 1290.390 us; speedup vs baseline: 3.4330x; 1.3160x over previous
//
#include <hip/hip_runtime.h>
#include <hip/hip_bf16.h>

// B=8, C=256, NH=8, DH=32, N=1024 (32x32), L=8, DFF=1025 (pad 1152)
// conv0: im2col (Ci=3) + MFMA GEMM. convs 1-7: implicit-GEMM (gather A-stage).
// Transformer: bf16 MFMA GEMMs (BM=64), pos folded into QKV epilogue,
// fp32 residual/LN, exact-sparse 7x7 attention (query-tiled, LDS-staged K/V).

typedef __bf16 bf16x8 __attribute__((ext_vector_type(8)));
typedef float f32x4 __attribute__((ext_vector_type(4)));
typedef unsigned short us8v __attribute__((ext_vector_type(8)));

__device__ __forceinline__ unsigned short f2bf(float f) {
  unsigned int u = __float_as_uint(f);
  unsigned int r = (u + 0x7fffu + ((u >> 16) & 1u)) >> 16;
  return (unsigned short)r;
}
__device__ __forceinline__ float bf2f(unsigned short h) {
  return __uint_as_float(((unsigned int)h) << 16);
}

#define GLD16(src, dst)                                                        \
  __builtin_amdgcn_global_load_lds(                                            \
      (const __attribute__((address_space(1))) unsigned int*)(src),            \
      (__attribute__((address_space(3))) unsigned int*)(dst), 16, 0, 0)

// ---------------- unified bf16 MFMA GEMM ----------------
// C[M,Npad] = A[M,K] @ B[Npad,K]^T (+bias +posadd, act), BN=128, BK=32.
// MODE 0: A linear [M][lda]. MODE 1: implicit conv gather from NHWC xin=A
//   (Ci%32==0, Hi==Wi, Wo = Hi/stride = 1<<lw, K = 9*Ci, M = Bz*Wo*Wo).
// act: 0 none, 1 relu, 2 silu. omode: 0 f32, 1 bf16, 2 both.
template<int BM, int MODE>
__global__ __launch_bounds__(256) void k_gemm(
    const unsigned short* __restrict__ A, int lda,
    const unsigned short* __restrict__ Bw, int ldb,
    const float* __restrict__ bias, const float* __restrict__ posadd,
    float* __restrict__ C, unsigned short* __restrict__ Cb, int ldc,
    int K, int Nstore, int act, int omode, long long zsB, long long zsC,
    const unsigned short* __restrict__ zpage, int Ci, int Hi, int stride, int lw)
{
  constexpr int ACH = BM / 64;     // A-chunk loads per thread
  constexpr int MF  = BM / 32;     // m fragments per wave
  __shared__ unsigned short lA[2][BM * 32];
  __shared__ unsigned short lB[2][128 * 32];
  int tid = threadIdx.x, lane = tid & 63, wid = tid >> 6;
  int bm = blockIdx.x * BM, bn = blockIdx.y << 7;
  const unsigned short* Bz = Bw + (size_t)blockIdx.z * zsB;
  int crow = lane >> 2, ckof = (lane & 3) << 3;
  const unsigned short* Bbase = Bz + (size_t)bn * ldb + ckof;
  const unsigned short* Abase = A + (size_t)bm * lda + ckof;

  int hb[ACH], wb[ACH];
  size_t ab[ACH];
  int dh = 0, dw = 0, cc = 0;
  if (MODE == 1) {
#pragma unroll
    for (int i = 0; i < ACH; ++i) {
      int c = (ACH == 2) ? wid * 2 + i : wid;
      int pos = bm + c * 16 + crow;
      int b = pos >> (2 * lw);
      int rem = pos & ((1 << (2 * lw)) - 1);
      int ho = rem >> lw, wo = rem & ((1 << lw) - 1);
      hb[i] = ho * stride - 1;
      wb[i] = wo * stride - 1;
      ab[i] = ((size_t)b * Hi * Hi) * Ci + ckof;
    }
  }

  auto stage = [&](int buf, int k0s) {
#pragma unroll
    for (int i = 0; i < ACH; ++i) {
      int c = (ACH == 2) ? wid * 2 + i : wid;
      if constexpr (MODE == 0) {
        int row = c * 16 + crow;
        GLD16(Abase + (size_t)row * lda + k0s, &lA[buf][c * 512]);
      } else {
        int hi = hb[i] + dh, wi = wb[i] + dw;
        const unsigned short* ap =
            ((unsigned)hi < (unsigned)Hi && (unsigned)wi < (unsigned)Hi)
                ? (A + ab[i] + ((size_t)hi * Hi + wi) * Ci + cc)
                : zpage;
        GLD16(ap, &lA[buf][c * 512]);
      }
    }
#pragma unroll
    for (int i = 0; i < 2; ++i) {
      int c = wid * 2 + i;
      int row = c * 16 + crow;
      GLD16(Bbase + (size_t)row * ldb + k0s, &lB[buf][c * 512]);
    }
  };
  auto adv = [&]() {
    if (MODE == 1) {
      cc += 32;
      if (cc >= Ci) { cc = 0; if (++dw == 3) { dw = 0; ++dh; } }
    }
  };

  f32x4 acc[MF][4];
#pragma unroll
  for (int m = 0; m < MF; ++m)
#pragma unroll
    for (int n = 0; n < 4; ++n)
#pragma unroll
      for (int j = 0; j < 4; ++j) acc[m][n][j] = 0.f;

  stage(0, 0);
  adv();
  int wm = wid >> 1, wn = wid & 1;
  int r0 = wm * (BM / 2) + (lane & 15);
  int c0 = wn * 64 + (lane & 15);
  int kq = (lane >> 4) << 3;
  int nkt = K >> 5, cur = 0;
  for (int kt = 0; kt < nkt; ++kt) {
    __syncthreads();
    if (kt + 1 < nkt) { stage(cur ^ 1, (kt + 1) << 5); adv(); }
    bf16x8 afr[MF], bfr[4];
#pragma unroll
    for (int m = 0; m < MF; ++m)
      afr[m] = *(const bf16x8*)&lA[cur][(r0 + m * 16) * 32 + kq];
#pragma unroll
    for (int n = 0; n < 4; ++n)
      bfr[n] = *(const bf16x8*)&lB[cur][(c0 + n * 16) * 32 + kq];
#pragma unroll
    for (int m = 0; m < MF; ++m)
#pragma unroll
      for (int n = 0; n < 4; ++n)
        acc[m][n] = __builtin_amdgcn_mfma_f32_16x16x32_bf16(afr[m], bfr[n], acc[m][n], 0, 0, 0);
    cur ^= 1;
  }

  float* Cz = C ? C + (size_t)blockIdx.z * zsC : nullptr;
  unsigned short* Cbz = Cb ? Cb + (size_t)blockIdx.z * zsC : nullptr;
  int colb = bn + wn * 64 + (lane & 15);
  int rowb = bm + wm * (BM / 2) + ((lane >> 4) << 2);
#pragma unroll
  for (int n = 0; n < 4; ++n) {
    int col = colb + n * 16;
    if (col >= Nstore) continue;
    float bs = bias ? bias[col] : 0.f;
#pragma unroll
    for (int m = 0; m < MF; ++m) {
#pragma unroll
      for (int j = 0; j < 4; ++j) {
        int row = rowb + m * 16 + j;
        float v = acc[m][n][j] + bs;
        if (posadd && col < 512) v += posadd[((row & 1023) << 9) + col];
        if (act == 1) v = fmaxf(v, 0.f);
        else if (act == 2) v = v / (1.f + __expf(-v));
        size_t off = (size_t)row * ldc + col;
        if (omode == 0) Cz[off] = v;
        else if (omode == 1) Cbz[off] = f2bf(v);
        else { Cz[off] = v; Cbz[off] = f2bf(v); }
      }
    }
  }
}

// ---------------- conv0 im2col: NCHW f32 hint -> [rows][32] bf16 ----------------
__global__ __launch_bounds__(256) void k_im2col0(
    const float* __restrict__ x, unsigned short* __restrict__ dst, int row0, int total)
{
  for (int idx = blockIdx.x * 256 + threadIdx.x; idx < total; idx += gridDim.x * 256) {
    int r = idx >> 5, e = idx & 31;
    int pos = row0 + r;
    int b = pos >> 16, rem = pos & 65535, ho = rem >> 8, wo = rem & 255;
    unsigned short val = 0;
    if (e < 27) {
      int t9 = e / 3, ci = e - t9 * 3;
      int hi = ho + (t9 / 3) - 1, wi = wo + (t9 - (t9 / 3) * 3) - 1;
      if ((unsigned)hi < 256u && (unsigned)wi < 256u)
        val = f2bf(x[(((size_t)b * 3 + ci) << 16) + (hi << 8) + wi]);
    }
    dst[idx] = val;
  }
}

// ---------------- conv weight permute: OIHW f32 -> [CoP][t*CiP+ci] bf16 ----------
__global__ __launch_bounds__(256) void k_wperm(
    const float* __restrict__ w, unsigned short* __restrict__ wp,
    int Co, int CiR, int CiP, int CoP, int Kpad)
{
  int idx = blockIdx.x * 256 + threadIdx.x;
  if (idx >= CoP * Kpad) return;
  int co = idx / Kpad, k = idx - co * Kpad;
  int t = k / CiP, ci = k - t * CiP;
  float v = 0.f;
  if (co < Co && t < 9 && ci < CiR) v = w[((size_t)co * CiR + ci) * 9 + t];
  wp[idx] = f2bf(v);
}

// ---------------- pad-convert fp32 -> bf16 / padded fp32, per layer slab --------
__global__ void k_cvt_pad(const float* __restrict__ in, unsigned short* __restrict__ outb,
                          float* __restrict__ outf, int R, int C, int Rp, int Cp)
{
  int l = blockIdx.y;
  int total = Rp * Cp;
  for (int idx = blockIdx.x * 256 + threadIdx.x; idx < total; idx += gridDim.x * 256) {
    int r = idx / Cp, c = idx - r * Cp;
    float v = (r < R && c < C) ? in[((size_t)l * R + r) * C + c] : 0.f;
    size_t o = (size_t)l * total + idx;
    if (outb) outb[o] = f2bf(v);
    if (outf) outf[o] = v;
  }
}

// ---------------- sine positional embedding (1024, 256) -> bf16 ----------------
__global__ __launch_bounds__(256) void k_pos(unsigned short* __restrict__ posb)
{
  int n = blockIdx.x, c = threadIdx.x;
  int ih = n >> 5, iw = n & 31;
  float coord = (c < 128) ? (float)(ih + 1) : (float)(iw + 1);
  int cc = c & 127;
  float e = (float)((cc >> 1) << 1) * (1.f / 128.f);
  float t = coord / powf(10000.f, e);
  posb[(n << 8) + c] = f2bf((cc & 1) ? cosf(t) : sinf(t));
}

// ---------------- neighborhood attention (7x7), query-tiled, LDS-staged --------
// Block = (b, 8x8 query tile) x head. Union K/V window (<=14x14=196 rows) staged
// to LDS once: K as f32 (row stride 36 -> bank-minimal b128), V bf16 via
// global_load_lds. Quad (4 lanes) per query: 8 dims/lane dot, 2-shfl reduce,
// two-pass softmax in LDS p (invalid keys -1e30 -> exp 0, exact), PV from LDS.
__global__ __launch_bounds__(256) void k_attn(
    const unsigned short* __restrict__ qkv, unsigned short* __restrict__ ctx)
{
  __shared__ float k_lds[196 * 36];          // 28224 B
  __shared__ unsigned short v_lds[848 * 8];  // 13568 B (64-slot overflow pad)
  __shared__ float p_lds[64 * 50];           // 12800 B
  int bx = blockIdx.x;
  int b = bx >> 4, tile = bx & 15;
  int th8 = ((tile >> 2) << 3), tw8 = ((tile & 3) << 3);
  int g = blockIdx.y;
  int tid = threadIdx.x, lane = tid & 63, wid = tid >> 6;
  int h0e = max(th8 - 3, 0), h1e = min(th8 + 10, 31);
  int w0e = max(tw8 - 3, 0), w1e = min(tw8 + 10, 31);
  int nh = h1e - h0e + 1, nw = w1e - w0e + 1;
  int nkeys = nh * nw, nslots = nkeys * 4;
  unsigned int magic = (65536u + (unsigned)nw - 1u) / (unsigned)nw;  // exact for our range
  size_t qbase = (size_t)((unsigned)b << 10) * 768;

  // stage K (bf16 global -> f32 LDS, row stride 36 floats)
  for (int s = tid; s < 784; s += 256) {
    int sc = min(s, nslots - 1);
    int uidx = sc >> 2, oct = sc & 3;
    int hh = (int)(((unsigned)uidx * magic) >> 16);
    int ww = uidx - hh * nw;
    hh += h0e; ww += w0e;
    const unsigned short* kp = qkv + qbase + (size_t)((hh << 5) + ww) * 768 + 256 + (g << 5) + oct * 8;
    us8v u = *(const us8v*)kp;
    float* dst = &k_lds[uidx * 36 + oct * 8];
    f32x4 w0, w1;
#pragma unroll
    for (int j = 0; j < 4; ++j) { w0[j] = bf2f(u[j]); w1[j] = bf2f(u[j + 4]); }
    *(f32x4*)dst = w0;
    *(f32x4*)(dst + 4) = w1;
  }
  // stage V (bf16 straight copy via global_load_lds; dest wave-uniform + lane*16)
#pragma unroll
  for (int i = 0; i < 4; ++i) {
    int base = i * 256 + wid * 64;
    if (base < 784) {
      int s = min(base + lane, nslots - 1);
      int uidx = s >> 2, chunk = s & 3;
      int hh = (int)(((unsigned)uidx * magic) >> 16);
      int ww = uidx - hh * nw;
      hh += h0e; ww += w0e;
      const unsigned short* vp = qkv + qbase + (size_t)((hh << 5) + ww) * 768 + 512 + (g << 5) + chunk * 8;
      GLD16(vp, &v_lds[base * 8]);
    }
  }
  __syncthreads();

  // per-thread query: quad layout (q = tid>>2, dq = tid&3 -> dims dq*8..+7)
  int q = tid >> 2, dq = tid & 3;
  int qh = th8 + (q >> 3), qw = tw8 + (q & 7);
  const float scale = 0.17677669529663687f;  // 1/sqrt(32)
  const unsigned short* qp = qkv + qbase + (size_t)((qh << 5) + qw) * 768 + (g << 5) + dq * 8;
  us8v uq = *(const us8v*)qp;
  float qr[8];
#pragma unroll
  for (int j = 0; j < 8; ++j) qr[j] = bf2f(uq[j]) * scale;

  int rbase[7], cofs[7];
  bool rval[7], cval[7];
#pragma unroll
  for (int d = 0; d < 7; ++d) {
    int mh = qh - 3 + d;
    rval[d] = (unsigned)mh < 32u;
    rbase[d] = (mh - h0e) * nw;
    int mw = qw - 3 + d;
    cval[d] = (unsigned)mw < 32u;
    cofs[d] = mw - w0e;
  }

  // phase A: 49 dots via quad, track max, raw scores -> p_lds
  float m = -1e30f;
#pragma unroll
  for (int kk = 0; kk < 49; ++kk) {
    const int d7 = kk / 7, r7 = kk % 7;
    bool valid = rval[d7] && cval[r7];
    int uidx = valid ? (rbase[d7] + cofs[r7]) : 0;
    const float* kr = &k_lds[uidx * 36 + dq * 8];
    f32x4 a0 = *(const f32x4*)kr, a1 = *(const f32x4*)(kr + 4);
    float d = 0.f;
#pragma unroll
    for (int j = 0; j < 4; ++j) d = fmaf(qr[j], a0[j], d);
#pragma unroll
    for (int j = 0; j < 4; ++j) d = fmaf(qr[4 + j], a1[j], d);
    d += __shfl_xor(d, 1);
    d += __shfl_xor(d, 2);
    float s_kk = valid ? d : -1e30f;
    m = fmaxf(m, s_kk);
    if (dq == (kk & 3)) p_lds[q * 50 + kk] = s_kk;
  }
  // softmax (two-pass, same wave -> no barrier needed)
  float sum = 0.f;
  for (int kk = dq; kk < 49; kk += 4) {
    float e = __expf(p_lds[q * 50 + kk] - m);
    p_lds[q * 50 + kk] = e;
    sum += e;
  }
  sum += __shfl_xor(sum, 1);
  sum += __shfl_xor(sum, 2);
  float inv = 1.f / sum;

  // phase B: PV from LDS (invalid keys have p==0, clamped read harmless)
  float acc[8] = {};
#pragma unroll
  for (int kk = 0; kk < 49; ++kk) {
    const int d7 = kk / 7, r7 = kk % 7;
    int uidx = (rval[d7] && cval[r7]) ? (rbase[d7] + cofs[r7]) : 0;
    float pb = p_lds[q * 50 + kk];
    us8v uv = *(const us8v*)&v_lds[uidx * 32 + dq * 8];
#pragma unroll
    for (int j = 0; j < 8; ++j) acc[j] = fmaf(pb, bf2f(uv[j]), acc[j]);
  }
  unsigned short* op = ctx + ((size_t)((b << 10) + (qh << 5) + qw) << 8) + (g << 5) + dq * 8;
  us8v out;
#pragma unroll
  for (int j = 0; j < 8; ++j) out[j] = f2bf(acc[j] * inv);
  *(us8v*)op = out;
}

// ---------------- fused residual add + LayerNorm, wave-per-row, no LDS ---------
__global__ __launch_bounds__(256) void k_add_ln(
    float* __restrict__ s, unsigned short* __restrict__ sb, const float* __restrict__ d,
    const float* __restrict__ g, const float* __restrict__ b)
{
  int row = (blockIdx.x << 2) + (threadIdx.x >> 6);
  int lane = threadIdx.x & 63;
  size_t base = ((size_t)row << 8) + (lane << 2);
  float4 x4 = *(float4*)(s + base);
  float4 d4 = *(const float4*)(d + base);
  x4.x += d4.x; x4.y += d4.y; x4.z += d4.z; x4.w += d4.w;
  float t = x4.x + x4.y + x4.z + x4.w;
  t += __shfl_xor(t, 1); t += __shfl_xor(t, 2); t += __shfl_xor(t, 4);
  t += __shfl_xor(t, 8); t += __shfl_xor(t, 16); t += __shfl_xor(t, 32);
  float mu = t * (1.f / 256.f);
  float e0 = x4.x - mu, e1 = x4.y - mu, e2 = x4.z - mu, e3 = x4.w - mu;
  float u = e0 * e0 + e1 * e1 + e2 * e2 + e3 * e3;
  u += __shfl_xor(u, 1); u += __shfl_xor(u, 2); u += __shfl_xor(u, 4);
  u += __shfl_xor(u, 8); u += __shfl_xor(u, 16); u += __shfl_xor(u, 32);
  float var = u * (1.f / 256.f);
  float r = rsqrtf(var + 1e-5f);
  float4 g4 = *(const float4*)(g + (lane << 2));
  float4 b4 = *(const float4*)(b + (lane << 2));
  float o0 = e0 * r * g4.x + b4.x;
  float o1 = e1 * r * g4.y + b4.y;
  float o2 = e2 * r * g4.z + b4.z;
  float o3 = e3 * r * g4.w + b4.w;
  float4 of = {o0, o1, o2, o3};
  *(float4*)(s + base) = of;
  ushort4 ob = {f2bf(o0), f2bf(o1), f2bf(o2), f2bf(o3)};
  *(ushort4*)(sb + base) = ob;
}

// ---------------- (B,1024,256) f32 -> (B,256,32,32) ----------------
__global__ void k_nxc_to_cxn(const float* __restrict__ x, float* __restrict__ y)
{
  __shared__ float t[32][33];
  int b = blockIdx.z;
  int c0 = blockIdx.x * 32, n0 = blockIdx.y * 32;
  int tx = threadIdx.x, ty = threadIdx.y;
  t[ty][tx] = x[((size_t)(b * 1024 + n0 + ty)) * 256 + c0 + tx];
  __syncthreads();
  y[((size_t)(b * 256 + c0 + ty)) * 1024 + n0 + tx] = t[tx][ty];
}

extern "C" void kernel_launch(void* const* d_in, const int* in_sizes, int n_in,
                              void* d_out, int out_size, void* d_ws, size_t ws_size,
                              hipStream_t stream)
{
  const float* hint = (const float*)d_in[0];
  const float* cw[8];
  for (int i = 0; i < 8; ++i) cw[i] = (const float*)d_in[1 + i];
  const float* ipw  = (const float*)d_in[9];
  const float* ipb  = (const float*)d_in[10];
  const float* outw = (const float*)d_in[11];
  const float* outb = (const float*)d_in[12];
  const float* l1w  = (const float*)d_in[13];
  const float* l1b  = (const float*)d_in[14];
  const float* l2w  = (const float*)d_in[15];
  const float* l2b  = (const float*)d_in[16];
  const float* g1   = (const float*)d_in[17];
  const float* b1   = (const float*)d_in[18];
  const float* g2   = (const float*)d_in[19];
  const float* b2   = (const float*)d_in[20];

  float* ws = (float*)d_ws;
  size_t off = 0;
  float* bufA = ws + off; off += 8388608;   // NHWC ping / qkvb+ctx
  float* bufB = ws + off; off += 8388608;   // NHWC pong / tmp+ff
  float* imb  = ws + off; off += 2097152;   // conv0 im2col chunk (131072 x 32 bf16)
  float* src  = ws + off; off += 2097152;   // (8192, 256) f32
  unsigned short* srcb = (unsigned short*)(ws + off); off += 1048576;
  unsigned short* posb = (unsigned short*)(ws + off); off += 131072;   // (1024,256)
  float* posqk = ws + off; off += 4194304;  // 8 x 1024 x 512 f32
  unsigned short* wqkvb = (unsigned short*)(ws + off); off += 786432;  // 8x768x256
  unsigned short* outwb = (unsigned short*)(ws + off); off += 262144;  // 8x256x256
  unsigned short* l1wb  = (unsigned short*)(ws + off); off += 1179648; // 8x1152x256
  unsigned short* l2wb  = (unsigned short*)(ws + off); off += 1179648; // 8x256x1152
  float* l1bp = ws + off; off += 9216;      // 8x1152
  unsigned short* cwp[8];
  const int CoPs[8]  = {128, 128, 128, 128, 128, 128, 256, 256};
  const int CiRs[8]  = {3, 16, 16, 32, 32, 96, 96, 256};
  const int CiPs[8]  = {3, 32, 32, 32, 32, 96, 96, 256};
  const int Kpads[8] = {32, 288, 288, 288, 288, 864, 864, 2304};
  const int Cos[8]   = {16, 16, 32, 32, 96, 96, 256, 256};
  for (int i = 0; i < 8; ++i) { cwp[i] = (unsigned short*)(ws + off); off += (size_t)CoPs[i] * Kpads[i] / 2; }
  unsigned short* zpage = (unsigned short*)(ws + off); off += 64;

  hipMemsetAsync(zpage, 0, 256, stream);

  // ---- weight prep ----
  k_cvt_pad<<<dim3(768, 8), 256, 0, stream>>>(ipw,  wqkvb, nullptr, 768, 256, 768, 256);
  k_cvt_pad<<<dim3(256, 8), 256, 0, stream>>>(outw, outwb, nullptr, 256, 256, 256, 256);
  k_cvt_pad<<<dim3(1152, 8), 256, 0, stream>>>(l1w, l1wb, nullptr, 1025, 256, 1152, 256);
  k_cvt_pad<<<dim3(1152, 8), 256, 0, stream>>>(l2w, l2wb, nullptr, 256, 1025, 256, 1152);
  k_cvt_pad<<<dim3(5, 8), 256, 0, stream>>>(l1b, nullptr, l1bp, 1025, 1, 1152, 1);
  for (int i = 0; i < 8; ++i)
    k_wperm<<<(CoPs[i] * Kpads[i] + 255) / 256, 256, 0, stream>>>(
        cw[i], cwp[i], Cos[i], CiRs[i], CiPs[i], CoPs[i], Kpads[i]);
  k_pos<<<dim3(1024), 256, 0, stream>>>(posb);

  unsigned short* bufAu = (unsigned short*)bufA;
  unsigned short* bufBu = (unsigned short*)bufB;
  unsigned short* imbu  = (unsigned short*)imb;

  // ---- conv0: im2col + GEMM, 4 chunks of 131072 rows -> bufA NHWC(32) ----
  for (int c = 0; c < 4; ++c) {
    k_im2col0<<<16384, 256, 0, stream>>>(hint, imbu, c * 131072, 131072 * 32);
    k_gemm<128, 0><<<dim3(1024, 1), 256, 0, stream>>>(
        imbu, 32, cwp[0], 32, nullptr, nullptr, nullptr,
        bufAu + (size_t)c * 131072 * 32, 32, 32, 32, 2, 1, 0, 0,
        nullptr, 0, 0, 0, 0);
  }
  // ---- convs 1-7: implicit GEMM ----
  k_gemm<128, 1><<<dim3(4096, 1), 256, 0, stream>>>(   // conv1: 256^2, s1
      bufAu, 0, cwp[1], 288, nullptr, nullptr, nullptr, bufBu, 32, 288, 32, 2, 1,
      0, 0, zpage, 32, 256, 1, 8);
  k_gemm<128, 1><<<dim3(1024, 1), 256, 0, stream>>>(   // conv2: ->128^2, s2
      bufBu, 0, cwp[2], 288, nullptr, nullptr, nullptr, bufAu, 32, 288, 32, 2, 1,
      0, 0, zpage, 32, 256, 2, 7);
  k_gemm<128, 1><<<dim3(1024, 1), 256, 0, stream>>>(   // conv3: 128^2, s1
      bufAu, 0, cwp[3], 288, nullptr, nullptr, nullptr, bufBu, 32, 288, 32, 2, 1,
      0, 0, zpage, 32, 128, 1, 7);
  k_gemm<128, 1><<<dim3(256, 1), 256, 0, stream>>>(    // conv4: ->64^2, s2, Co96
      bufBu, 0, cwp[4], 288, nullptr, nullptr, nullptr, bufAu, 96, 288, 96, 2, 1,
      0, 0, zpage, 32, 128, 2, 6);
  k_gemm<128, 1><<<dim3(256, 1), 256, 0, stream>>>(    // conv5: 64^2, s1
      bufAu, 0, cwp[5], 864, nullptr, nullptr, nullptr, bufBu, 96, 864, 96, 2, 1,
      0, 0, zpage, 96, 64, 1, 6);
  k_gemm<64, 1><<<dim3(128, 2), 256, 0, stream>>>(     // conv6: ->32^2, s2, Co256
      bufBu, 0, cwp[6], 864, nullptr, nullptr, nullptr, bufAu, 256, 864, 256, 2, 1,
      0, 0, zpage, 96, 64, 2, 5);
  k_gemm<64, 1><<<dim3(128, 2), 256, 0, stream>>>(     // conv7: 32^2, s1, no act
      bufAu, 0, cwp[7], 2304, nullptr, nullptr, src, srcb, 256, 2304, 256, 0, 2,
      0, 0, zpage, 256, 32, 1, 5);

  // ---- posqk[l] = pos @ [Wq;Wk]^T, batched over 8 layers ----
  k_gemm<64, 0><<<dim3(16, 4, 8), 256, 0, stream>>>(
      posb, 256, wqkvb, 256, nullptr, nullptr, posqk, nullptr, 512, 256, 512, 0, 0,
      196608LL, 524288LL, nullptr, 0, 0, 0, 0);

  // in-transformer overlays
  unsigned short* qkvb = bufAu;                                  // 8192 x 768 bf16
  unsigned short* ctx  = (unsigned short*)(bufA + 3145728);      // 8192 x 256 bf16
  float* tmp           = bufB;                                   // 8192 x 256 f32
  unsigned short* ff   = (unsigned short*)(bufB + 2097152);      // 8192 x 1152 bf16

  // ---- transformer layers ----
  for (int l = 0; l < 8; ++l) {
    const unsigned short* wqkv_l = wqkvb + (size_t)l * 768 * 256;
    const float* ipb_l  = ipb  + (size_t)l * 768;
    const unsigned short* outw_l = outwb + (size_t)l * 256 * 256;
    const float* outb_l = outb + (size_t)l * 256;
    const unsigned short* l1w_l = l1wb + (size_t)l * 1152 * 256;
    const float* l1b_l  = l1bp + (size_t)l * 1152;
    const unsigned short* l2w_l = l2wb + (size_t)l * 256 * 1152;
    const float* l2b_l  = l2b  + (size_t)l * 256;
    const float* posqk_l = posqk + (size_t)l * 524288;
    const float* g1_l = g1 + l * 256; const float* b1_l = b1 + l * 256;
    const float* g2_l = g2 + l * 256; const float* b2_l = b2 + l * 256;

    k_gemm<64, 0><<<dim3(128, 6), 256, 0, stream>>>(   // QKV, pos folded into q,k
        srcb, 256, wqkv_l, 256, ipb_l, posqk_l, nullptr, qkvb, 768, 256, 768, 0, 1,
        0, 0, nullptr, 0, 0, 0, 0);
    k_attn<<<dim3(128, 8), 256, 0, stream>>>(qkvb, ctx);
    k_gemm<64, 0><<<dim3(128, 2), 256, 0, stream>>>(   // out proj
        ctx, 256, outw_l, 256, outb_l, nullptr, tmp, nullptr, 256, 256, 256, 0, 0,
        0, 0, nullptr, 0, 0, 0, 0);
    k_add_ln<<<dim3(2048), 256, 0, stream>>>(src, srcb, tmp, g1_l, b1_l);
    k_gemm<64, 0><<<dim3(128, 9), 256, 0, stream>>>(   // lin1 + relu
        srcb, 256, l1w_l, 256, l1b_l, nullptr, nullptr, ff, 1152, 256, 1152, 1, 1,
        0, 0, nullptr, 0, 0, 0, 0);
    k_gemm<64, 0><<<dim3(128, 2), 256, 0, stream>>>(   // lin2
        ff, 1152, l2w_l, 1152, l2b_l, nullptr, tmp, nullptr, 256, 1152, 256, 0, 0,
        0, 0, nullptr, 0, 0, 0, 0);
    k_add_ln<<<dim3(2048), 256, 0, stream>>>(src, srcb, tmp, g2_l, b2_l);
  }

  // ---- output ----
  k_nxc_to_cxn<<<dim3(8, 32, 8), dim3(32, 32), 0, stream>>>(src, (float*)d_out);
}

// Round 6
// 1212.592 us; speedup vs baseline: 3.6533x; 1.0642x over previous
//
#include <hip/hip_runtime.h>
#include <hip/hip_bf16.h>

// B=8, C=256, NH=8, DH=32, N=1024 (32x32), L=8, DFF=1025 (pad 1152)
// conv0: im2col (Ci=3) + MFMA GEMM. convs 1-7: implicit-GEMM (gather A-stage).
// GEMM: XOR-swizzled LDS (pre-swizzled global source, rule #21), BN=32 variant
// for Co<=32 convs. Transformer: bf16 MFMA GEMMs, pos folded into QKV epilogue,
// fp32 residual/LN, exact-sparse 7x7 attention (query-tiled, LDS-staged K/V).

typedef __bf16 bf16x8 __attribute__((ext_vector_type(8)));
typedef float f32x4 __attribute__((ext_vector_type(4)));
typedef unsigned short us8v __attribute__((ext_vector_type(8)));

__device__ __forceinline__ unsigned short f2bf(float f) {
  unsigned int u = __float_as_uint(f);
  unsigned int r = (u + 0x7fffu + ((u >> 16) & 1u)) >> 16;
  return (unsigned short)r;
}
__device__ __forceinline__ float bf2f(unsigned short h) {
  return __uint_as_float(((unsigned int)h) << 16);
}

#define GLD16(src, dst)                                                        \
  __builtin_amdgcn_global_load_lds(                                            \
      (const __attribute__((address_space(1))) unsigned int*)(src),            \
      (__attribute__((address_space(3))) unsigned int*)(dst), 16, 0, 0)

// ---------------- unified bf16 MFMA GEMM ----------------
// C[M,Npad] = A[M,K] @ B[Npad,K]^T (+bias +posadd, act), BK=32.
// LDS tiles [rows][32] bf16; 16B chunk j of row r stored at slot j^((r>>1)&3)
// via pre-swizzled GLOBAL source (LDS dest stays linear for global_load_lds);
// reads apply the same XOR -> full 32-bank spread on ds_read_b128.
// MODE 0: A linear [M][lda]. MODE 1: implicit conv gather from NHWC xin=A
//   (Ci%32==0, Hi==Wi, Wo = Hi/stride = 1<<lw, K = 9*Ci, M = Bz*Wo*Wo).
// act: 0 none, 1 relu, 2 silu. omode: 0 f32, 1 bf16, 2 both.
template<int BM, int BN, int MODE>
__global__ __launch_bounds__(256) void k_gemm(
    const unsigned short* __restrict__ A, int lda,
    const unsigned short* __restrict__ Bw, int ldb,
    const float* __restrict__ bias, const float* __restrict__ posadd,
    float* __restrict__ C, unsigned short* __restrict__ Cb, int ldc,
    int K, int Nstore, int act, int omode, long long zsB, long long zsC,
    const unsigned short* __restrict__ zpage, int Ci, int Hi, int stride, int lw)
{
  constexpr int NWN = (BN >= 128) ? 2 : 1;     // waves along N
  constexpr int NWM = 4 / NWN;                 // waves along M
  constexpr int WM = BM / NWM, WN = BN / NWN;  // wave tile
  constexpr int MF = WM / 16, NF = WN / 16;    // fragments per wave
  constexpr int ACH = BM / 64;                 // A-stage iterations per thread
  __shared__ unsigned short lA[2][BM * 32];
  __shared__ unsigned short lB[2][BN * 32];
  int tid = threadIdx.x, lane = tid & 63, wid = tid >> 6;
  int bm = blockIdx.x * BM, bn = blockIdx.y * BN;
  const unsigned short* Bz = Bw + (size_t)blockIdx.z * zsB;
  int crow = lane >> 2;                                   // row within 16-row chunk
  int cksw = (((lane & 3) ^ ((crow >> 1) & 3)) << 3);     // swizzled k-chunk offset
  const unsigned short* Bbase = Bz + (size_t)bn * ldb + cksw;
  const unsigned short* Abase = A + (size_t)bm * lda + cksw;

  int hb[ACH], wb[ACH];
  size_t ab[ACH];
  int dh = 0, dw = 0, cc = 0;
  if (MODE == 1) {
#pragma unroll
    for (int i = 0; i < ACH; ++i) {
      int c = wid + i * 4;
      int pos = bm + c * 16 + crow;
      int b = pos >> (2 * lw);
      int rem = pos & ((1 << (2 * lw)) - 1);
      int ho = rem >> lw, wo = rem & ((1 << lw) - 1);
      hb[i] = ho * stride - 1;
      wb[i] = wo * stride - 1;
      ab[i] = ((size_t)b * Hi * Hi) * Ci + cksw;
    }
  }

  auto stage = [&](int buf, int k0s) {
#pragma unroll
    for (int i = 0; i < ACH; ++i) {
      int c = wid + i * 4;
      if constexpr (MODE == 0) {
        int row = c * 16 + crow;
        GLD16(Abase + (size_t)row * lda + k0s, &lA[buf][c * 512]);
      } else {
        int hi = hb[i] + dh, wi = wb[i] + dw;
        const unsigned short* ap =
            ((unsigned)hi < (unsigned)Hi && (unsigned)wi < (unsigned)Hi)
                ? (A + ab[i] + ((size_t)hi * Hi + wi) * Ci + cc)
                : zpage;
        GLD16(ap, &lA[buf][c * 512]);
      }
    }
#pragma unroll
    for (int i = 0; i < (BN / 16 + 3) / 4; ++i) {
      int c = wid + i * 4;
      if (BN / 16 >= 4 || c < BN / 16) {
        int row = c * 16 + crow;
        GLD16(Bbase + (size_t)row * ldb + k0s, &lB[buf][c * 512]);
      }
    }
  };
  auto adv = [&]() {
    if (MODE == 1) {
      cc += 32;
      if (cc >= Ci) { cc = 0; if (++dw == 3) { dw = 0; ++dh; } }
    }
  };

  f32x4 acc[MF][NF];
#pragma unroll
  for (int m = 0; m < MF; ++m)
#pragma unroll
    for (int n = 0; n < NF; ++n)
#pragma unroll
      for (int j = 0; j < 4; ++j) acc[m][n][j] = 0.f;

  stage(0, 0);
  adv();
  int wn = wid % NWN, wm = wid / NWN;
  int r0 = wm * WM + (lane & 15);
  int c0 = wn * WN + (lane & 15);
  int sw = (lane >> 1) & 3;                  // (row>>1)&3 for fragment rows
  int kqs = ((lane >> 4) ^ sw) << 3;         // swizzled read chunk offset
  int nkt = K >> 5, cur = 0;
  for (int kt = 0; kt < nkt; ++kt) {
    __syncthreads();
    if (kt + 1 < nkt) { stage(cur ^ 1, (kt + 1) << 5); adv(); }
    bf16x8 afr[MF], bfr[NF];
#pragma unroll
    for (int m = 0; m < MF; ++m)
      afr[m] = *(const bf16x8*)&lA[cur][(r0 + m * 16) * 32 + kqs];
#pragma unroll
    for (int n = 0; n < NF; ++n)
      bfr[n] = *(const bf16x8*)&lB[cur][(c0 + n * 16) * 32 + kqs];
#pragma unroll
    for (int m = 0; m < MF; ++m)
#pragma unroll
      for (int n = 0; n < NF; ++n)
        acc[m][n] = __builtin_amdgcn_mfma_f32_16x16x32_bf16(afr[m], bfr[n], acc[m][n], 0, 0, 0);
    cur ^= 1;
  }

  float* Cz = C ? C + (size_t)blockIdx.z * zsC : nullptr;
  unsigned short* Cbz = Cb ? Cb + (size_t)blockIdx.z * zsC : nullptr;
  int colb = bn + wn * WN + (lane & 15);
  int rowb = bm + wm * WM + ((lane >> 4) << 2);
#pragma unroll
  for (int n = 0; n < NF; ++n) {
    int col = colb + n * 16;
    if (col >= Nstore) continue;
    float bs = bias ? bias[col] : 0.f;
#pragma unroll
    for (int m = 0; m < MF; ++m) {
#pragma unroll
      for (int j = 0; j < 4; ++j) {
        int row = rowb + m * 16 + j;
        float v = acc[m][n][j] + bs;
        if (posadd && col < 512) v += posadd[((row & 1023) << 9) + col];
        if (act == 1) v = fmaxf(v, 0.f);
        else if (act == 2) v = v / (1.f + __expf(-v));
        size_t off = (size_t)row * ldc + col;
        if (omode == 0) Cz[off] = v;
        else if (omode == 1) Cbz[off] = f2bf(v);
        else { Cz[off] = v; Cbz[off] = f2bf(v); }
      }
    }
  }
}

// ---------------- conv0 im2col: NCHW f32 hint -> [rows][32] bf16 ----------------
__global__ __launch_bounds__(256) void k_im2col0(
    const float* __restrict__ x, unsigned short* __restrict__ dst, int row0, int total)
{
  for (int idx = blockIdx.x * 256 + threadIdx.x; idx < total; idx += gridDim.x * 256) {
    int r = idx >> 5, e = idx & 31;
    int pos = row0 + r;
    int b = pos >> 16, rem = pos & 65535, ho = rem >> 8, wo = rem & 255;
    unsigned short val = 0;
    if (e < 27) {
      int t9 = e / 3, ci = e - t9 * 3;
      int hi = ho + (t9 / 3) - 1, wi = wo + (t9 - (t9 / 3) * 3) - 1;
      if ((unsigned)hi < 256u && (unsigned)wi < 256u)
        val = f2bf(x[(((size_t)b * 3 + ci) << 16) + (hi << 8) + wi]);
    }
    dst[idx] = val;
  }
}

// ---------------- conv weight permute: OIHW f32 -> [CoP][t*CiP+ci] bf16 ----------
__global__ __launch_bounds__(256) void k_wperm(
    const float* __restrict__ w, unsigned short* __restrict__ wp,
    int Co, int CiR, int CiP, int CoP, int Kpad)
{
  int idx = blockIdx.x * 256 + threadIdx.x;
  if (idx >= CoP * Kpad) return;
  int co = idx / Kpad, k = idx - co * Kpad;
  int t = k / CiP, ci = k - t * CiP;
  float v = 0.f;
  if (co < Co && t < 9 && ci < CiR) v = w[((size_t)co * CiR + ci) * 9 + t];
  wp[idx] = f2bf(v);
}

// ---------------- pad-convert fp32 -> bf16 / padded fp32, per layer slab --------
__global__ void k_cvt_pad(const float* __restrict__ in, unsigned short* __restrict__ outb,
                          float* __restrict__ outf, int R, int C, int Rp, int Cp)
{
  int l = blockIdx.y;
  int total = Rp * Cp;
  for (int idx = blockIdx.x * 256 + threadIdx.x; idx < total; idx += gridDim.x * 256) {
    int r = idx / Cp, c = idx - r * Cp;
    float v = (r < R && c < C) ? in[((size_t)l * R + r) * C + c] : 0.f;
    size_t o = (size_t)l * total + idx;
    if (outb) outb[o] = f2bf(v);
    if (outf) outf[o] = v;
  }
}

// ---------------- sine positional embedding (1024, 256) -> bf16 ----------------
__global__ __launch_bounds__(256) void k_pos(unsigned short* __restrict__ posb)
{
  int n = blockIdx.x, c = threadIdx.x;
  int ih = n >> 5, iw = n & 31;
  float coord = (c < 128) ? (float)(ih + 1) : (float)(iw + 1);
  int cc = c & 127;
  float e = (float)((cc >> 1) << 1) * (1.f / 128.f);
  float t = coord / powf(10000.f, e);
  posb[(n << 8) + c] = f2bf((cc & 1) ? cosf(t) : sinf(t));
}

// ---------------- neighborhood attention (7x7), query-tiled, LDS-staged --------
__global__ __launch_bounds__(256) void k_attn(
    const unsigned short* __restrict__ qkv, unsigned short* __restrict__ ctx)
{
  __shared__ float k_lds[196 * 36];          // 28224 B
  __shared__ unsigned short v_lds[848 * 8];  // 13568 B (64-slot overflow pad)
  __shared__ float p_lds[64 * 50];           // 12800 B
  int bx = blockIdx.x;
  int b = bx >> 4, tile = bx & 15;
  int th8 = ((tile >> 2) << 3), tw8 = ((tile & 3) << 3);
  int g = blockIdx.y;
  int tid = threadIdx.x, lane = tid & 63, wid = tid >> 6;
  int h0e = max(th8 - 3, 0), h1e = min(th8 + 10, 31);
  int w0e = max(tw8 - 3, 0), w1e = min(tw8 + 10, 31);
  int nh = h1e - h0e + 1, nw = w1e - w0e + 1;
  int nkeys = nh * nw, nslots = nkeys * 4;
  unsigned int magic = (65536u + (unsigned)nw - 1u) / (unsigned)nw;  // exact for our range
  size_t qbase = (size_t)((unsigned)b << 10) * 768;

  // stage K (bf16 global -> f32 LDS, row stride 36 floats)
  for (int s = tid; s < 784; s += 256) {
    int sc = min(s, nslots - 1);
    int uidx = sc >> 2, oct = sc & 3;
    int hh = (int)(((unsigned)uidx * magic) >> 16);
    int ww = uidx - hh * nw;
    hh += h0e; ww += w0e;
    const unsigned short* kp = qkv + qbase + (size_t)((hh << 5) + ww) * 768 + 256 + (g << 5) + oct * 8;
    us8v u = *(const us8v*)kp;
    float* dst = &k_lds[uidx * 36 + oct * 8];
    f32x4 w0, w1;
#pragma unroll
    for (int j = 0; j < 4; ++j) { w0[j] = bf2f(u[j]); w1[j] = bf2f(u[j + 4]); }
    *(f32x4*)dst = w0;
    *(f32x4*)(dst + 4) = w1;
  }
  // stage V (bf16 straight copy via global_load_lds; dest wave-uniform + lane*16)
#pragma unroll
  for (int i = 0; i < 4; ++i) {
    int base = i * 256 + wid * 64;
    if (base < 784) {
      int s = min(base + lane, nslots - 1);
      int uidx = s >> 2, chunk = s & 3;
      int hh = (int)(((unsigned)uidx * magic) >> 16);
      int ww = uidx - hh * nw;
      hh += h0e; ww += w0e;
      const unsigned short* vp = qkv + qbase + (size_t)((hh << 5) + ww) * 768 + 512 + (g << 5) + chunk * 8;
      GLD16(vp, &v_lds[base * 8]);
    }
  }
  __syncthreads();

  // per-thread query: quad layout (q = tid>>2, dq = tid&3 -> dims dq*8..+7)
  int q = tid >> 2, dq = tid & 3;
  int qh = th8 + (q >> 3), qw = tw8 + (q & 7);
  const float scale = 0.17677669529663687f;  // 1/sqrt(32)
  const unsigned short* qp = qkv + qbase + (size_t)((qh << 5) + qw) * 768 + (g << 5) + dq * 8;
  us8v uq = *(const us8v*)qp;
  float qr[8];
#pragma unroll
  for (int j = 0; j < 8; ++j) qr[j] = bf2f(uq[j]) * scale;

  int rbase[7], cofs[7];
  bool rval[7], cval[7];
#pragma unroll
  for (int d = 0; d < 7; ++d) {
    int mh = qh - 3 + d;
    rval[d] = (unsigned)mh < 32u;
    rbase[d] = (mh - h0e) * nw;
    int mw = qw - 3 + d;
    cval[d] = (unsigned)mw < 32u;
    cofs[d] = mw - w0e;
  }

  // phase A: 49 dots via quad, track max, raw scores -> p_lds
  float m = -1e30f;
#pragma unroll
  for (int kk = 0; kk < 49; ++kk) {
    const int d7 = kk / 7, r7 = kk % 7;
    bool valid = rval[d7] && cval[r7];
    int uidx = valid ? (rbase[d7] + cofs[r7]) : 0;
    const float* kr = &k_lds[uidx * 36 + dq * 8];
    f32x4 a0 = *(const f32x4*)kr, a1 = *(const f32x4*)(kr + 4);
    float d = 0.f;
#pragma unroll
    for (int j = 0; j < 4; ++j) d = fmaf(qr[j], a0[j], d);
#pragma unroll
    for (int j = 0; j < 4; ++j) d = fmaf(qr[4 + j], a1[j], d);
    d += __shfl_xor(d, 1);
    d += __shfl_xor(d, 2);
    float s_kk = valid ? d : -1e30f;
    m = fmaxf(m, s_kk);
    if (dq == (kk & 3)) p_lds[q * 50 + kk] = s_kk;
  }
  // softmax (two-pass, same wave -> no barrier needed)
  float sum = 0.f;
  for (int kk = dq; kk < 49; kk += 4) {
    float e = __expf(p_lds[q * 50 + kk] - m);
    p_lds[q * 50 + kk] = e;
    sum += e;
  }
  sum += __shfl_xor(sum, 1);
  sum += __shfl_xor(sum, 2);
  float inv = 1.f / sum;

  // phase B: PV from LDS (invalid keys have p==0, clamped read harmless)
  float acc[8] = {};
#pragma unroll
  for (int kk = 0; kk < 49; ++kk) {
    const int d7 = kk / 7, r7 = kk % 7;
    int uidx = (rval[d7] && cval[r7]) ? (rbase[d7] + cofs[r7]) : 0;
    float pb = p_lds[q * 50 + kk];
    us8v uv = *(const us8v*)&v_lds[uidx * 32 + dq * 8];
#pragma unroll
    for (int j = 0; j < 8; ++j) acc[j] = fmaf(pb, bf2f(uv[j]), acc[j]);
  }
  unsigned short* op = ctx + ((size_t)((b << 10) + (qh << 5) + qw) << 8) + (g << 5) + dq * 8;
  us8v out;
#pragma unroll
  for (int j = 0; j < 8; ++j) out[j] = f2bf(acc[j] * inv);
  *(us8v*)op = out;
}

// ---------------- fused residual add + LayerNorm, wave-per-row, no LDS ---------
__global__ __launch_bounds__(256) void k_add_ln(
    float* __restrict__ s, unsigned short* __restrict__ sb, const float* __restrict__ d,
    const float* __restrict__ g, const float* __restrict__ b)
{
  int row = (blockIdx.x << 2) + (threadIdx.x >> 6);
  int lane = threadIdx.x & 63;
  size_t base = ((size_t)row << 8) + (lane << 2);
  float4 x4 = *(float4*)(s + base);
  float4 d4 = *(const float4*)(d + base);
  x4.x += d4.x; x4.y += d4.y; x4.z += d4.z; x4.w += d4.w;
  float t = x4.x + x4.y + x4.z + x4.w;
  t += __shfl_xor(t, 1); t += __shfl_xor(t, 2); t += __shfl_xor(t, 4);
  t += __shfl_xor(t, 8); t += __shfl_xor(t, 16); t += __shfl_xor(t, 32);
  float mu = t * (1.f / 256.f);
  float e0 = x4.x - mu, e1 = x4.y - mu, e2 = x4.z - mu, e3 = x4.w - mu;
  float u = e0 * e0 + e1 * e1 + e2 * e2 + e3 * e3;
  u += __shfl_xor(u, 1); u += __shfl_xor(u, 2); u += __shfl_xor(u, 4);
  u += __shfl_xor(u, 8); u += __shfl_xor(u, 16); u += __shfl_xor(u, 32);
  float var = u * (1.f / 256.f);
  float r = rsqrtf(var + 1e-5f);
  float4 g4 = *(const float4*)(g + (lane << 2));
  float4 b4 = *(const float4*)(b + (lane << 2));
  float o0 = e0 * r * g4.x + b4.x;
  float o1 = e1 * r * g4.y + b4.y;
  float o2 = e2 * r * g4.z + b4.z;
  float o3 = e3 * r * g4.w + b4.w;
  float4 of = {o0, o1, o2, o3};
  *(float4*)(s + base) = of;
  ushort4 ob = {f2bf(o0), f2bf(o1), f2bf(o2), f2bf(o3)};
  *(ushort4*)(sb + base) = ob;
}

// ---------------- (B,1024,256) f32 -> (B,256,32,32) ----------------
__global__ void k_nxc_to_cxn(const float* __restrict__ x, float* __restrict__ y)
{
  __shared__ float t[32][33];
  int b = blockIdx.z;
  int c0 = blockIdx.x * 32, n0 = blockIdx.y * 32;
  int tx = threadIdx.x, ty = threadIdx.y;
  t[ty][tx] = x[((size_t)(b * 1024 + n0 + ty)) * 256 + c0 + tx];
  __syncthreads();
  y[((size_t)(b * 256 + c0 + ty)) * 1024 + n0 + tx] = t[tx][ty];
}

extern "C" void kernel_launch(void* const* d_in, const int* in_sizes, int n_in,
                              void* d_out, int out_size, void* d_ws, size_t ws_size,
                              hipStream_t stream)
{
  const float* hint = (const float*)d_in[0];
  const float* cw[8];
  for (int i = 0; i < 8; ++i) cw[i] = (const float*)d_in[1 + i];
  const float* ipw  = (const float*)d_in[9];
  const float* ipb  = (const float*)d_in[10];
  const float* outw = (const float*)d_in[11];
  const float* outb = (const float*)d_in[12];
  const float* l1w  = (const float*)d_in[13];
  const float* l1b  = (const float*)d_in[14];
  const float* l2w  = (const float*)d_in[15];
  const float* l2b  = (const float*)d_in[16];
  const float* g1   = (const float*)d_in[17];
  const float* b1   = (const float*)d_in[18];
  const float* g2   = (const float*)d_in[19];
  const float* b2   = (const float*)d_in[20];

  float* ws = (float*)d_ws;
  size_t off = 0;
  float* bufA = ws + off; off += 8388608;   // NHWC ping / qkvb+ctx
  float* bufB = ws + off; off += 8388608;   // NHWC pong / tmp+ff
  float* imb  = ws + off; off += 2097152;   // conv0 im2col chunk (131072 x 32 bf16)
  float* src  = ws + off; off += 2097152;   // (8192, 256) f32
  unsigned short* srcb = (unsigned short*)(ws + off); off += 1048576;
  unsigned short* posb = (unsigned short*)(ws + off); off += 131072;   // (1024,256)
  float* posqk = ws + off; off += 4194304;  // 8 x 1024 x 512 f32
  unsigned short* wqkvb = (unsigned short*)(ws + off); off += 786432;  // 8x768x256
  unsigned short* outwb = (unsigned short*)(ws + off); off += 262144;  // 8x256x256
  unsigned short* l1wb  = (unsigned short*)(ws + off); off += 1179648; // 8x1152x256
  unsigned short* l2wb  = (unsigned short*)(ws + off); off += 1179648; // 8x256x1152
  float* l1bp = ws + off; off += 9216;      // 8x1152
  unsigned short* cwp[8];
  const int CoPs[8]  = {128, 128, 128, 128, 128, 128, 256, 256};
  const int CiRs[8]  = {3, 16, 16, 32, 32, 96, 96, 256};
  const int CiPs[8]  = {3, 32, 32, 32, 32, 96, 96, 256};
  const int Kpads[8] = {32, 288, 288, 288, 288, 864, 864, 2304};
  const int Cos[8]   = {16, 16, 32, 32, 96, 96, 256, 256};
  for (int i = 0; i < 8; ++i) { cwp[i] = (unsigned short*)(ws + off); off += (size_t)CoPs[i] * Kpads[i] / 2; }
  unsigned short* zpage = (unsigned short*)(ws + off); off += 64;

  hipMemsetAsync(zpage, 0, 256, stream);

  // ---- weight prep ----
  k_cvt_pad<<<dim3(768, 8), 256, 0, stream>>>(ipw,  wqkvb, nullptr, 768, 256, 768, 256);
  k_cvt_pad<<<dim3(256, 8), 256, 0, stream>>>(outw, outwb, nullptr, 256, 256, 256, 256);
  k_cvt_pad<<<dim3(1152, 8), 256, 0, stream>>>(l1w, l1wb, nullptr, 1025, 256, 1152, 256);
  k_cvt_pad<<<dim3(1152, 8), 256, 0, stream>>>(l2w, l2wb, nullptr, 256, 1025, 256, 1152);
  k_cvt_pad<<<dim3(5, 8), 256, 0, stream>>>(l1b, nullptr, l1bp, 1025, 1, 1152, 1);
  for (int i = 0; i < 8; ++i)
    k_wperm<<<(CoPs[i] * Kpads[i] + 255) / 256, 256, 0, stream>>>(
        cw[i], cwp[i], Cos[i], CiRs[i], CiPs[i], CoPs[i], Kpads[i]);
  k_pos<<<dim3(1024), 256, 0, stream>>>(posb);

  unsigned short* bufAu = (unsigned short*)bufA;
  unsigned short* bufBu = (unsigned short*)bufB;
  unsigned short* imbu  = (unsigned short*)imb;

  // ---- conv0: im2col + GEMM (BN=32), 4 chunks of 131072 rows -> bufA NHWC(32) ----
  for (int c = 0; c < 4; ++c) {
    k_im2col0<<<16384, 256, 0, stream>>>(hint, imbu, c * 131072, 131072 * 32);
    k_gemm<128, 32, 0><<<dim3(1024, 1), 256, 0, stream>>>(
        imbu, 32, cwp[0], 32, nullptr, nullptr, nullptr,
        bufAu + (size_t)c * 131072 * 32, 32, 32, 32, 2, 1, 0, 0,
        nullptr, 0, 0, 0, 0);
  }
  // ---- convs 1-7: implicit GEMM ----
  k_gemm<128, 32, 1><<<dim3(4096, 1), 256, 0, stream>>>(   // conv1: 256^2, s1
      bufAu, 0, cwp[1], 288, nullptr, nullptr, nullptr, bufBu, 32, 288, 32, 2, 1,
      0, 0, zpage, 32, 256, 1, 8);
  k_gemm<128, 32, 1><<<dim3(1024, 1), 256, 0, stream>>>(   // conv2: ->128^2, s2
      bufBu, 0, cwp[2], 288, nullptr, nullptr, nullptr, bufAu, 32, 288, 32, 2, 1,
      0, 0, zpage, 32, 256, 2, 7);
  k_gemm<128, 32, 1><<<dim3(1024, 1), 256, 0, stream>>>(   // conv3: 128^2, s1
      bufAu, 0, cwp[3], 288, nullptr, nullptr, nullptr, bufBu, 32, 288, 32, 2, 1,
      0, 0, zpage, 32, 128, 1, 7);
  k_gemm<128, 128, 1><<<dim3(256, 1), 256, 0, stream>>>(   // conv4: ->64^2, s2, Co96
      bufBu, 0, cwp[4], 288, nullptr, nullptr, nullptr, bufAu, 96, 288, 96, 2, 1,
      0, 0, zpage, 32, 128, 2, 6);
  k_gemm<128, 128, 1><<<dim3(256, 1), 256, 0, stream>>>(   // conv5: 64^2, s1
      bufAu, 0, cwp[5], 864, nullptr, nullptr, nullptr, bufBu, 96, 864, 96, 2, 1,
      0, 0, zpage, 96, 64, 1, 6);
  k_gemm<64, 128, 1><<<dim3(128, 2), 256, 0, stream>>>(    // conv6: ->32^2, s2, Co256
      bufBu, 0, cwp[6], 864, nullptr, nullptr, nullptr, bufAu, 256, 864, 256, 2, 1,
      0, 0, zpage, 96, 64, 2, 5);
  k_gemm<64, 128, 1><<<dim3(128, 2), 256, 0, stream>>>(    // conv7: 32^2, s1, no act
      bufAu, 0, cwp[7], 2304, nullptr, nullptr, src, srcb, 256, 2304, 256, 0, 2,
      0, 0, zpage, 256, 32, 1, 5);

  // ---- posqk[l] = pos @ [Wq;Wk]^T, batched over 8 layers ----
  k_gemm<64, 128, 0><<<dim3(16, 4, 8), 256, 0, stream>>>(
      posb, 256, wqkvb, 256, nullptr, nullptr, posqk, nullptr, 512, 256, 512, 0, 0,
      196608LL, 524288LL, nullptr, 0, 0, 0, 0);

  // in-transformer overlays
  unsigned short* qkvb = bufAu;                                  // 8192 x 768 bf16
  unsigned short* ctx  = (unsigned short*)(bufA + 3145728);      // 8192 x 256 bf16
  float* tmp           = bufB;                                   // 8192 x 256 f32
  unsigned short* ff   = (unsigned short*)(bufB + 2097152);      // 8192 x 1152 bf16

  // ---- transformer layers ----
  for (int l = 0; l < 8; ++l) {
    const unsigned short* wqkv_l = wqkvb + (size_t)l * 768 * 256;
    const float* ipb_l  = ipb  + (size_t)l * 768;
    const unsigned short* outw_l = outwb + (size_t)l * 256 * 256;
    const float* outb_l = outb + (size_t)l * 256;
    const unsigned short* l1w_l = l1wb + (size_t)l * 1152 * 256;
    const float* l1b_l  = l1bp + (size_t)l * 1152;
    const unsigned short* l2w_l = l2wb + (size_t)l * 256 * 1152;
    const float* l2b_l  = l2b  + (size_t)l * 256;
    const float* posqk_l = posqk + (size_t)l * 524288;
    const float* g1_l = g1 + l * 256; const float* b1_l = b1 + l * 256;
    const float* g2_l = g2 + l * 256; const float* b2_l = b2 + l * 256;

    k_gemm<64, 128, 0><<<dim3(128, 6), 256, 0, stream>>>(   // QKV, pos folded into q,k
        srcb, 256, wqkv_l, 256, ipb_l, posqk_l, nullptr, qkvb, 768, 256, 768, 0, 1,
        0, 0, nullptr, 0, 0, 0, 0);
    k_attn<<<dim3(128, 8), 256, 0, stream>>>(qkvb, ctx);
    k_gemm<64, 128, 0><<<dim3(128, 2), 256, 0, stream>>>(   // out proj
        ctx, 256, outw_l, 256, outb_l, nullptr, tmp, nullptr, 256, 256, 256, 0, 0,
        0, 0, nullptr, 0, 0, 0, 0);
    k_add_ln<<<dim3(2048), 256, 0, stream>>>(src, srcb, tmp, g1_l, b1_l);
    k_gemm<64, 128, 0><<<dim3(128, 9), 256, 0, stream>>>(   // lin1 + relu
        srcb, 256, l1w_l, 256, l1b_l, nullptr, nullptr, ff, 1152, 256, 1152, 1, 1,
        0, 0, nullptr, 0, 0, 0, 0);
    k_gemm<64, 128, 0><<<dim3(128, 2), 256, 0, stream>>>(   // lin2
        ff, 1152, l2w_l, 1152, l2b_l, nullptr, tmp, nullptr, 256, 1152, 256, 0, 0,
        0, 0, nullptr, 0, 0, 0, 0);
    k_add_ln<<<dim3(2048), 256, 0, stream>>>(src, srcb, tmp, g2_l, b2_l);
  }

  // ---- output ----
  k_nxc_to_cxn<<<dim3(8, 32, 8), dim3(32, 32), 0, stream>>>(src, (float*)d_out);
}

// Round 7
// 1135.848 us; speedup vs baseline: 3.9001x; 1.0676x over previous
//
#include <hip/hip_runtime.h>
#include <hip/hip_bf16.h>

// B=8, C=256, NH=8, DH=32, N=1024 (32x32), L=8, DFF=1025 (pad 1152)
// conv0: im2col (Ci=3, K pad 64) + MFMA GEMM. convs 1-7: implicit-GEMM gather.
// GEMM: BK=64, 3-bit XOR LDS swizzle (pre-swizzled global source, rule #21).
// out-proj and lin2 GEMMs fuse residual-add + LayerNorm (BN=256 full row).
// Exact-sparse 7x7 attention (query-tiled, LDS-staged K/V).

typedef __bf16 bf16x8 __attribute__((ext_vector_type(8)));
typedef float f32x4 __attribute__((ext_vector_type(4)));
typedef unsigned short us8v __attribute__((ext_vector_type(8)));

__device__ __forceinline__ unsigned short f2bf(float f) {
  unsigned int u = __float_as_uint(f);
  unsigned int r = (u + 0x7fffu + ((u >> 16) & 1u)) >> 16;
  return (unsigned short)r;
}
__device__ __forceinline__ float bf2f(unsigned short h) {
  return __uint_as_float(((unsigned int)h) << 16);
}

#define GLD16(src, dst)                                                        \
  __builtin_amdgcn_global_load_lds(                                            \
      (const __attribute__((address_space(1))) unsigned int*)(src),            \
      (__attribute__((address_space(3))) unsigned int*)(dst), 16, 0, 0)

// ---------------- unified bf16 MFMA GEMM, BK=64 ----------------
// C[M,Npad] = A[M,K] @ B[Npad,K]^T (+bias +posadd, act). K % 64 == 0.
// LDS tile rows are 128B (8 x 16B chunks); chunk j of row r stored at slot
// j ^ (r&7) by pre-swizzling the GLOBAL source chunk (LDS dest stays linear,
// global_load_lds writes base+lane*16). Reads use the same XOR.
// MODE 0: A linear. MODE 1: implicit conv gather from NHWC (Ci%32==0, Hi==Wi,
//   Wo = Hi/stride = 1<<lw, K = taps*32-padded, M = Bz*Wo*Wo). tap = ksub*divm>>divs.
// LNF 1: BM=32,BN=256; epilogue does s = LN(s + out + bias) -> C (f32) + Cb (bf16).
template<int BM, int BN, int MODE, int LNF = 0>
__global__ __launch_bounds__(256) void k_gemm(
    const unsigned short* __restrict__ A, int lda,
    const unsigned short* __restrict__ Bw, int ldb,
    const float* __restrict__ bias, const float* __restrict__ posadd,
    float* __restrict__ C, unsigned short* __restrict__ Cb, int ldc,
    int K, int Nstore, int act, int omode, long long zsB, long long zsC,
    const unsigned short* __restrict__ zpage, int Ci, int Hi, int stride, int lw,
    int divm, int divs, const float* __restrict__ lng, const float* __restrict__ lnb)
{
  constexpr int NWN = (BN >= 128) ? 2 : 1;
  constexpr int NWM = 4 / NWN;
  constexpr int WM = BM / NWM, WN = BN / NWN;
  constexpr int MF = WM / 16, NF = WN / 16;
  constexpr int AIS = BM / 32;   // A global_load_lds issues per thread
  constexpr int BIS = BN / 32;
  __shared__ unsigned short lA[2][BM * 64];
  __shared__ unsigned short lB[2][BN * 64];
  __shared__ float red[2][32][2];
  int tid = threadIdx.x, lane = tid & 63, wid = tid >> 6;
  int bm = blockIdx.x * BM, bn = blockIdx.y * BN;
  const unsigned short* Bz = Bw + (size_t)blockIdx.z * zsB;

  int j = (lane & 7) ^ (lane >> 3);   // source chunk this lane fetches
  int e8 = (j & 3) << 3;              // element offset within a 32-ch half
  int halfl = j >> 2;                 // which k-half (tap) this lane serves

  size_t arow[AIS], brow[BIS];
  int hb[AIS], wb[AIS];
  size_t ab[AIS];
#pragma unroll
  for (int i = 0; i < AIS; ++i) {
    int rr = (wid + i * 4) * 8 + (lane >> 3);
    if constexpr (MODE == 0) {
      arow[i] = (size_t)(bm + rr) * lda + (j << 3);
    } else {
      int pos = bm + rr;
      int b = pos >> (2 * lw);
      int rem = pos & ((1 << (2 * lw)) - 1);
      int ho = rem >> lw, wo = rem & ((1 << lw) - 1);
      hb[i] = ho * stride - 1;
      wb[i] = wo * stride - 1;
      ab[i] = (size_t)b * Hi * Hi * Ci;
    }
  }
#pragma unroll
  for (int i = 0; i < BIS; ++i)
    brow[i] = (size_t)(bn + (wid + i * 4) * 8 + (lane >> 3)) * ldb + (j << 3);

  auto stage = [&](int buf, int kt) {
    if constexpr (MODE == 1) {
      int s0 = kt * 2, s1 = s0 + 1;
      int t0 = (s0 * divm) >> divs, t1 = (s1 * divm) >> divs;
      int cipw = Ci >> 5;
      int cc0 = (s0 - t0 * cipw) << 5, cc1 = (s1 - t1 * cipw) << 5;
      int kh0 = (t0 * 171) >> 9, kw0 = t0 - kh0 * 3;
      int kh1 = (t1 * 171) >> 9, kw1 = t1 - kh1 * 3;
      int kh = halfl ? kh1 : kh0;
      int kw = halfl ? kw1 : kw0;
      int cco = halfl ? cc1 : cc0;
      bool tv = (halfl ? t1 : t0) < 9;
#pragma unroll
      for (int i = 0; i < AIS; ++i) {
        int hi = hb[i] + kh, wi = wb[i] + kw;
        const unsigned short* ap =
            (tv && (unsigned)hi < (unsigned)Hi && (unsigned)wi < (unsigned)Hi)
                ? (A + ab[i] + (size_t)(hi * Hi + wi) * Ci + cco + e8)
                : zpage;
        GLD16(ap, &lA[buf][(wid + i * 4) * 512]);
      }
    } else {
#pragma unroll
      for (int i = 0; i < AIS; ++i)
        GLD16(A + arow[i] + kt * 64, &lA[buf][(wid + i * 4) * 512]);
    }
#pragma unroll
    for (int i = 0; i < BIS; ++i)
      GLD16(Bz + brow[i] + kt * 64, &lB[buf][(wid + i * 4) * 512]);
  };

  f32x4 acc[MF][NF];
#pragma unroll
  for (int m = 0; m < MF; ++m)
#pragma unroll
    for (int n = 0; n < NF; ++n)
#pragma unroll
      for (int q = 0; q < 4; ++q) acc[m][n][q] = 0.f;

  int wn = wid % NWN, wm = wid / NWN;
  int r0 = wm * WM + (lane & 15);
  int c0 = wn * WN + (lane & 15);
  int sl0 = (((lane >> 4)) ^ (lane & 7)) << 3;      // kk=0 slot (ushort offset)
  int sl1 = (((lane >> 4) + 4) ^ (lane & 7)) << 3;  // kk=1 slot
  int nkt = K >> 6, cur = 0;
  stage(0, 0);
  for (int kt = 0; kt < nkt; ++kt) {
    __syncthreads();
    if (kt + 1 < nkt) stage(cur ^ 1, kt + 1);
    bf16x8 a0[MF], a1[MF], b0[NF], b1[NF];
#pragma unroll
    for (int m = 0; m < MF; ++m) {
      a0[m] = *(const bf16x8*)&lA[cur][(r0 + m * 16) * 64 + sl0];
      a1[m] = *(const bf16x8*)&lA[cur][(r0 + m * 16) * 64 + sl1];
    }
#pragma unroll
    for (int n = 0; n < NF; ++n) {
      b0[n] = *(const bf16x8*)&lB[cur][(c0 + n * 16) * 64 + sl0];
      b1[n] = *(const bf16x8*)&lB[cur][(c0 + n * 16) * 64 + sl1];
    }
#pragma unroll
    for (int m = 0; m < MF; ++m)
#pragma unroll
      for (int n = 0; n < NF; ++n)
        acc[m][n] = __builtin_amdgcn_mfma_f32_16x16x32_bf16(a0[m], b0[n], acc[m][n], 0, 0, 0);
#pragma unroll
    for (int m = 0; m < MF; ++m)
#pragma unroll
      for (int n = 0; n < NF; ++n)
        acc[m][n] = __builtin_amdgcn_mfma_f32_16x16x32_bf16(a1[m], b1[n], acc[m][n], 0, 0, 0);
    cur ^= 1;
  }

  int colb = bn + wn * WN + (lane & 15);
  int rowb = bm + wm * WM + ((lane >> 4) << 2);

  if constexpr (LNF) {
    // BM=32, BN=256: full row per block. x = s + (acc + bias); LN over 256 cols.
    float x[NF][4];
    float sums[4] = {0.f, 0.f, 0.f, 0.f}, sqs[4] = {0.f, 0.f, 0.f, 0.f};
#pragma unroll
    for (int n = 0; n < NF; ++n) {
      int col = colb + n * 16;
      float bs = bias[col];
#pragma unroll
      for (int q = 0; q < 4; ++q) {
        int row = rowb + q;
        float v = acc[0][n][q] + bs + C[(size_t)row * 256 + col];
        x[n][q] = v;
        sums[q] += v;
        sqs[q] += v * v;
      }
    }
#pragma unroll
    for (int q = 0; q < 4; ++q) {
      sums[q] += __shfl_xor(sums[q], 1); sqs[q] += __shfl_xor(sqs[q], 1);
      sums[q] += __shfl_xor(sums[q], 2); sqs[q] += __shfl_xor(sqs[q], 2);
      sums[q] += __shfl_xor(sums[q], 4); sqs[q] += __shfl_xor(sqs[q], 4);
      sums[q] += __shfl_xor(sums[q], 8); sqs[q] += __shfl_xor(sqs[q], 8);
    }
    int rl = wm * 16 + ((lane >> 4) << 2);
    if ((lane & 15) == 0) {
#pragma unroll
      for (int q = 0; q < 4; ++q) {
        red[wn][rl + q][0] = sums[q];
        red[wn][rl + q][1] = sqs[q];
      }
    }
    __syncthreads();
#pragma unroll
    for (int q = 0; q < 4; ++q) {
      float ts = sums[q] + red[wn ^ 1][rl + q][0];
      float tq = sqs[q] + red[wn ^ 1][rl + q][1];
      float mu = ts * (1.f / 256.f);
      float var = tq * (1.f / 256.f) - mu * mu;
      float rs = rsqrtf(var + 1e-5f);
      int row = rowb + q;
#pragma unroll
      for (int n = 0; n < NF; ++n) {
        int col = colb + n * 16;
        float o = (x[n][q] - mu) * rs * lng[col] + lnb[col];
        C[(size_t)row * 256 + col] = o;
        Cb[(size_t)row * 256 + col] = f2bf(o);
      }
    }
    return;
  }

  float* Cz = C ? C + (size_t)blockIdx.z * zsC : nullptr;
  unsigned short* Cbz = Cb ? Cb + (size_t)blockIdx.z * zsC : nullptr;
#pragma unroll
  for (int n = 0; n < NF; ++n) {
    int col = colb + n * 16;
    if (col >= Nstore) continue;
    float bs = bias ? bias[col] : 0.f;
#pragma unroll
    for (int m = 0; m < MF; ++m) {
#pragma unroll
      for (int q = 0; q < 4; ++q) {
        int row = rowb + m * 16 + q;
        float v = acc[m][n][q] + bs;
        if (posadd && col < 512) v += posadd[((row & 1023) << 9) + col];
        if (act == 1) v = fmaxf(v, 0.f);
        else if (act == 2) v = v / (1.f + __expf(-v));
        size_t off = (size_t)row * ldc + col;
        if (omode == 0) Cz[off] = v;
        else if (omode == 1) Cbz[off] = f2bf(v);
        else { Cz[off] = v; Cbz[off] = f2bf(v); }
      }
    }
  }
}

// ---------------- conv0 im2col: NCHW f32 hint -> [rows][64] bf16 ----------------
__global__ __launch_bounds__(256) void k_im2col0(
    const float* __restrict__ x, unsigned short* __restrict__ dst, int row0, int total)
{
  for (int idx = blockIdx.x * 256 + threadIdx.x; idx < total; idx += gridDim.x * 256) {
    int r = idx >> 6, e = idx & 63;
    int pos = row0 + r;
    int b = pos >> 16, rem = pos & 65535, ho = rem >> 8, wo = rem & 255;
    unsigned short val = 0;
    if (e < 27) {
      int t9 = e / 3, ci = e - t9 * 3;
      int hi = ho + (t9 / 3) - 1, wi = wo + (t9 - (t9 / 3) * 3) - 1;
      if ((unsigned)hi < 256u && (unsigned)wi < 256u)
        val = f2bf(x[(((size_t)b * 3 + ci) << 16) + (hi << 8) + wi]);
    }
    dst[idx] = val;
  }
}

// ---------------- conv weight permute: OIHW f32 -> [CoP][t*CiP+ci] bf16 ----------
__global__ __launch_bounds__(256) void k_wperm(
    const float* __restrict__ w, unsigned short* __restrict__ wp,
    int Co, int CiR, int CiP, int CoP, int Kpad)
{
  int idx = blockIdx.x * 256 + threadIdx.x;
  if (idx >= CoP * Kpad) return;
  int co = idx / Kpad, k = idx - co * Kpad;
  int t = k / CiP, ci = k - t * CiP;
  float v = 0.f;
  if (co < Co && t < 9 && ci < CiR) v = w[((size_t)co * CiR + ci) * 9 + t];
  wp[idx] = f2bf(v);
}

// ---------------- pad-convert fp32 -> bf16 / padded fp32, per layer slab --------
__global__ void k_cvt_pad(const float* __restrict__ in, unsigned short* __restrict__ outb,
                          float* __restrict__ outf, int R, int C, int Rp, int Cp)
{
  int l = blockIdx.y;
  int total = Rp * Cp;
  for (int idx = blockIdx.x * 256 + threadIdx.x; idx < total; idx += gridDim.x * 256) {
    int r = idx / Cp, c = idx - r * Cp;
    float v = (r < R && c < C) ? in[((size_t)l * R + r) * C + c] : 0.f;
    size_t o = (size_t)l * total + idx;
    if (outb) outb[o] = f2bf(v);
    if (outf) outf[o] = v;
  }
}

// ---------------- sine positional embedding (1024, 256) -> bf16 ----------------
__global__ __launch_bounds__(256) void k_pos(unsigned short* __restrict__ posb)
{
  int n = blockIdx.x, c = threadIdx.x;
  int ih = n >> 5, iw = n & 31;
  float coord = (c < 128) ? (float)(ih + 1) : (float)(iw + 1);
  int cc = c & 127;
  float e = (float)((cc >> 1) << 1) * (1.f / 128.f);
  float t = coord / powf(10000.f, e);
  posb[(n << 8) + c] = f2bf((cc & 1) ? cosf(t) : sinf(t));
}

// ---------------- neighborhood attention (7x7), query-tiled, LDS-staged --------
__global__ __launch_bounds__(256) void k_attn(
    const unsigned short* __restrict__ qkv, unsigned short* __restrict__ ctx)
{
  __shared__ float k_lds[196 * 36];          // 28224 B
  __shared__ unsigned short v_lds[848 * 8];  // 13568 B (64-slot overflow pad)
  __shared__ float p_lds[64 * 50];           // 12800 B
  int bx = blockIdx.x;
  int b = bx >> 4, tile = bx & 15;
  int th8 = ((tile >> 2) << 3), tw8 = ((tile & 3) << 3);
  int g = blockIdx.y;
  int tid = threadIdx.x, lane = tid & 63, wid = tid >> 6;
  int h0e = max(th8 - 3, 0), h1e = min(th8 + 10, 31);
  int w0e = max(tw8 - 3, 0), w1e = min(tw8 + 10, 31);
  int nh = h1e - h0e + 1, nw = w1e - w0e + 1;
  int nkeys = nh * nw, nslots = nkeys * 4;
  unsigned int magic = (65536u + (unsigned)nw - 1u) / (unsigned)nw;
  size_t qbase = (size_t)((unsigned)b << 10) * 768;

  for (int s = tid; s < 784; s += 256) {
    int sc = min(s, nslots - 1);
    int uidx = sc >> 2, oct = sc & 3;
    int hh = (int)(((unsigned)uidx * magic) >> 16);
    int ww = uidx - hh * nw;
    hh += h0e; ww += w0e;
    const unsigned short* kp = qkv + qbase + (size_t)((hh << 5) + ww) * 768 + 256 + (g << 5) + oct * 8;
    us8v u = *(const us8v*)kp;
    float* dst = &k_lds[uidx * 36 + oct * 8];
    f32x4 w0, w1;
#pragma unroll
    for (int q = 0; q < 4; ++q) { w0[q] = bf2f(u[q]); w1[q] = bf2f(u[q + 4]); }
    *(f32x4*)dst = w0;
    *(f32x4*)(dst + 4) = w1;
  }
#pragma unroll
  for (int i = 0; i < 4; ++i) {
    int base = i * 256 + wid * 64;
    if (base < 784) {
      int s = min(base + lane, nslots - 1);
      int uidx = s >> 2, chunk = s & 3;
      int hh = (int)(((unsigned)uidx * magic) >> 16);
      int ww = uidx - hh * nw;
      hh += h0e; ww += w0e;
      const unsigned short* vp = qkv + qbase + (size_t)((hh << 5) + ww) * 768 + 512 + (g << 5) + chunk * 8;
      GLD16(vp, &v_lds[base * 8]);
    }
  }
  __syncthreads();

  int q = tid >> 2, dq = tid & 3;
  int qh = th8 + (q >> 3), qw = tw8 + (q & 7);
  const float scale = 0.17677669529663687f;  // 1/sqrt(32)
  const unsigned short* qp = qkv + qbase + (size_t)((qh << 5) + qw) * 768 + (g << 5) + dq * 8;
  us8v uq = *(const us8v*)qp;
  float qr[8];
#pragma unroll
  for (int t = 0; t < 8; ++t) qr[t] = bf2f(uq[t]) * scale;

  int rbase[7], cofs[7];
  bool rval[7], cval[7];
#pragma unroll
  for (int d = 0; d < 7; ++d) {
    int mh = qh - 3 + d;
    rval[d] = (unsigned)mh < 32u;
    rbase[d] = (mh - h0e) * nw;
    int mw = qw - 3 + d;
    cval[d] = (unsigned)mw < 32u;
    cofs[d] = mw - w0e;
  }

  float m = -1e30f;
#pragma unroll
  for (int kk = 0; kk < 49; ++kk) {
    const int d7 = kk / 7, r7 = kk % 7;
    bool valid = rval[d7] && cval[r7];
    int uidx = valid ? (rbase[d7] + cofs[r7]) : 0;
    const float* kr = &k_lds[uidx * 36 + dq * 8];
    f32x4 a0 = *(const f32x4*)kr, a1 = *(const f32x4*)(kr + 4);
    float d = 0.f;
#pragma unroll
    for (int t = 0; t < 4; ++t) d = fmaf(qr[t], a0[t], d);
#pragma unroll
    for (int t = 0; t < 4; ++t) d = fmaf(qr[4 + t], a1[t], d);
    d += __shfl_xor(d, 1);
    d += __shfl_xor(d, 2);
    float s_kk = valid ? d : -1e30f;
    m = fmaxf(m, s_kk);
    if (dq == (kk & 3)) p_lds[q * 50 + kk] = s_kk;
  }
  float sum = 0.f;
  for (int kk = dq; kk < 49; kk += 4) {
    float e = __expf(p_lds[q * 50 + kk] - m);
    p_lds[q * 50 + kk] = e;
    sum += e;
  }
  sum += __shfl_xor(sum, 1);
  sum += __shfl_xor(sum, 2);
  float inv = 1.f / sum;

  float acc[8] = {};
#pragma unroll
  for (int kk = 0; kk < 49; ++kk) {
    const int d7 = kk / 7, r7 = kk % 7;
    int uidx = (rval[d7] && cval[r7]) ? (rbase[d7] + cofs[r7]) : 0;
    float pb = p_lds[q * 50 + kk];
    us8v uv = *(const us8v*)&v_lds[uidx * 32 + dq * 8];
#pragma unroll
    for (int t = 0; t < 8; ++t) acc[t] = fmaf(pb, bf2f(uv[t]), acc[t]);
  }
  unsigned short* op = ctx + ((size_t)((b << 10) + (qh << 5) + qw) << 8) + (g << 5) + dq * 8;
  us8v out;
#pragma unroll
  for (int t = 0; t < 8; ++t) out[t] = f2bf(acc[t] * inv);
  *(us8v*)op = out;
}

// ---------------- (B,1024,256) f32 -> (B,256,32,32) ----------------
__global__ void k_nxc_to_cxn(const float* __restrict__ x, float* __restrict__ y)
{
  __shared__ float t[32][33];
  int b = blockIdx.z;
  int c0 = blockIdx.x * 32, n0 = blockIdx.y * 32;
  int tx = threadIdx.x, ty = threadIdx.y;
  t[ty][tx] = x[((size_t)(b * 1024 + n0 + ty)) * 256 + c0 + tx];
  __syncthreads();
  y[((size_t)(b * 256 + c0 + ty)) * 1024 + n0 + tx] = t[tx][ty];
}

extern "C" void kernel_launch(void* const* d_in, const int* in_sizes, int n_in,
                              void* d_out, int out_size, void* d_ws, size_t ws_size,
                              hipStream_t stream)
{
  const float* hint = (const float*)d_in[0];
  const float* cw[8];
  for (int i = 0; i < 8; ++i) cw[i] = (const float*)d_in[1 + i];
  const float* ipw  = (const float*)d_in[9];
  const float* ipb  = (const float*)d_in[10];
  const float* outw = (const float*)d_in[11];
  const float* outb = (const float*)d_in[12];
  const float* l1w  = (const float*)d_in[13];
  const float* l1b  = (const float*)d_in[14];
  const float* l2w  = (const float*)d_in[15];
  const float* l2b  = (const float*)d_in[16];
  const float* g1   = (const float*)d_in[17];
  const float* b1   = (const float*)d_in[18];
  const float* g2   = (const float*)d_in[19];
  const float* b2   = (const float*)d_in[20];

  float* ws = (float*)d_ws;
  size_t off = 0;
  float* bufA = ws + off; off += 8388608;   // NHWC ping / qkvb+ctx
  float* bufB = ws + off; off += 8388608;   // NHWC pong / im2col chunk / ff
  float* src  = ws + off; off += 2097152;   // (8192, 256) f32
  unsigned short* srcb = (unsigned short*)(ws + off); off += 1048576;
  unsigned short* posb = (unsigned short*)(ws + off); off += 131072;   // (1024,256)
  float* posqk = ws + off; off += 4194304;  // 8 x 1024 x 512 f32
  unsigned short* wqkvb = (unsigned short*)(ws + off); off += 786432;  // 8x768x256
  unsigned short* outwb = (unsigned short*)(ws + off); off += 262144;  // 8x256x256
  unsigned short* l1wb  = (unsigned short*)(ws + off); off += 1179648; // 8x1152x256
  unsigned short* l2wb  = (unsigned short*)(ws + off); off += 1179648; // 8x256x1152
  float* l1bp = ws + off; off += 9216;      // 8x1152
  unsigned short* cwp[8];
  const int CoPs[8]  = {128, 128, 128, 128, 128, 128, 256, 256};
  const int CiRs[8]  = {3, 16, 16, 32, 32, 96, 96, 256};
  const int CiPs[8]  = {3, 32, 32, 32, 32, 96, 96, 256};
  const int Kpads[8] = {64, 320, 320, 320, 320, 896, 896, 2304};
  const int Cos[8]   = {16, 16, 32, 32, 96, 96, 256, 256};
  for (int i = 0; i < 8; ++i) { cwp[i] = (unsigned short*)(ws + off); off += (size_t)CoPs[i] * Kpads[i] / 2; }
  unsigned short* zpage = (unsigned short*)(ws + off); off += 64;

  hipMemsetAsync(zpage, 0, 256, stream);

  // ---- weight prep ----
  k_cvt_pad<<<dim3(768, 8), 256, 0, stream>>>(ipw,  wqkvb, nullptr, 768, 256, 768, 256);
  k_cvt_pad<<<dim3(256, 8), 256, 0, stream>>>(outw, outwb, nullptr, 256, 256, 256, 256);
  k_cvt_pad<<<dim3(1152, 8), 256, 0, stream>>>(l1w, l1wb, nullptr, 1025, 256, 1152, 256);
  k_cvt_pad<<<dim3(1152, 8), 256, 0, stream>>>(l2w, l2wb, nullptr, 256, 1025, 256, 1152);
  k_cvt_pad<<<dim3(5, 8), 256, 0, stream>>>(l1b, nullptr, l1bp, 1025, 1, 1152, 1);
  for (int i = 0; i < 8; ++i)
    k_wperm<<<(CoPs[i] * Kpads[i] + 255) / 256, 256, 0, stream>>>(
        cw[i], cwp[i], Cos[i], CiRs[i], CiPs[i], CoPs[i], Kpads[i]);
  k_pos<<<dim3(1024), 256, 0, stream>>>(posb);

  unsigned short* bufAu = (unsigned short*)bufA;
  unsigned short* bufBu = (unsigned short*)bufB;
  unsigned short* imbu  = (unsigned short*)bufB;   // conv0 im2col chunk (16MB < 32MB)

#define GEMM_TAIL nullptr, 0, 0, 0, 0, 0, 0, nullptr, nullptr
  // ---- conv0: im2col + GEMM (BN=32, K=64), 4 chunks -> bufA NHWC(32) ----
  for (int c = 0; c < 4; ++c) {
    k_im2col0<<<8192, 256, 0, stream>>>(hint, imbu, c * 131072, 131072 * 64);
    k_gemm<128, 32, 0><<<dim3(1024, 1), 256, 0, stream>>>(
        imbu, 64, cwp[0], 64, nullptr, nullptr, nullptr,
        bufAu + (size_t)c * 131072 * 32, 32, 64, 32, 2, 1, 0, 0, GEMM_TAIL);
  }
  // ---- convs 1-7: implicit GEMM (zpage, Ci, Hi, stride, lw, divm, divs) ----
  k_gemm<128, 32, 1><<<dim3(4096, 1), 256, 0, stream>>>(   // conv1: 256^2, s1
      bufAu, 0, cwp[1], 320, nullptr, nullptr, nullptr, bufBu, 32, 320, 32, 2, 1,
      0, 0, zpage, 32, 256, 1, 8, 1, 0, nullptr, nullptr);
  k_gemm<128, 32, 1><<<dim3(1024, 1), 256, 0, stream>>>(   // conv2: ->128^2, s2
      bufBu, 0, cwp[2], 320, nullptr, nullptr, nullptr, bufAu, 32, 320, 32, 2, 1,
      0, 0, zpage, 32, 256, 2, 7, 1, 0, nullptr, nullptr);
  k_gemm<128, 32, 1><<<dim3(1024, 1), 256, 0, stream>>>(   // conv3: 128^2, s1
      bufAu, 0, cwp[3], 320, nullptr, nullptr, nullptr, bufBu, 32, 320, 32, 2, 1,
      0, 0, zpage, 32, 128, 1, 7, 1, 0, nullptr, nullptr);
  k_gemm<128, 128, 1><<<dim3(256, 1), 256, 0, stream>>>(   // conv4: ->64^2, s2, Co96
      bufBu, 0, cwp[4], 320, nullptr, nullptr, nullptr, bufAu, 96, 320, 96, 2, 1,
      0, 0, zpage, 32, 128, 2, 6, 1, 0, nullptr, nullptr);
  k_gemm<128, 128, 1><<<dim3(256, 1), 256, 0, stream>>>(   // conv5: 64^2, s1
      bufAu, 0, cwp[5], 896, nullptr, nullptr, nullptr, bufBu, 96, 896, 96, 2, 1,
      0, 0, zpage, 96, 64, 1, 6, 171, 9, nullptr, nullptr);
  k_gemm<64, 128, 1><<<dim3(128, 2), 256, 0, stream>>>(    // conv6: ->32^2, s2, Co256
      bufBu, 0, cwp[6], 896, nullptr, nullptr, nullptr, bufAu, 256, 896, 256, 2, 1,
      0, 0, zpage, 96, 64, 2, 5, 171, 9, nullptr, nullptr);
  k_gemm<64, 128, 1><<<dim3(128, 2), 256, 0, stream>>>(    // conv7: 32^2, s1, no act
      bufAu, 0, cwp[7], 2304, nullptr, nullptr, src, srcb, 256, 2304, 256, 0, 2,
      0, 0, zpage, 256, 32, 1, 5, 1, 3, nullptr, nullptr);

  // ---- posqk[l] = pos @ [Wq;Wk]^T, batched over 8 layers ----
  k_gemm<64, 128, 0><<<dim3(16, 4, 8), 256, 0, stream>>>(
      posb, 256, wqkvb, 256, nullptr, nullptr, posqk, nullptr, 512, 256, 512, 0, 0,
      196608LL, 524288LL, GEMM_TAIL);

  // in-transformer overlays
  unsigned short* qkvb = bufAu;                                  // 8192 x 768 bf16
  unsigned short* ctx  = (unsigned short*)(bufA + 3145728);      // 8192 x 256 bf16
  unsigned short* ff   = (unsigned short*)(bufB + 2097152);      // 8192 x 1152 bf16

  // ---- transformer layers ----
  for (int l = 0; l < 8; ++l) {
    const unsigned short* wqkv_l = wqkvb + (size_t)l * 768 * 256;
    const float* ipb_l  = ipb  + (size_t)l * 768;
    const unsigned short* outw_l = outwb + (size_t)l * 256 * 256;
    const float* outb_l = outb + (size_t)l * 256;
    const unsigned short* l1w_l = l1wb + (size_t)l * 1152 * 256;
    const float* l1b_l  = l1bp + (size_t)l * 1152;
    const unsigned short* l2w_l = l2wb + (size_t)l * 256 * 1152;
    const float* l2b_l  = l2b  + (size_t)l * 256;
    const float* posqk_l = posqk + (size_t)l * 524288;
    const float* g1_l = g1 + l * 256; const float* b1_l = b1 + l * 256;
    const float* g2_l = g2 + l * 256; const float* b2_l = b2 + l * 256;

    k_gemm<64, 128, 0><<<dim3(128, 6), 256, 0, stream>>>(   // QKV, pos folded in
        srcb, 256, wqkv_l, 256, ipb_l, posqk_l, nullptr, qkvb, 768, 256, 768, 0, 1,
        0, 0, GEMM_TAIL);
    k_attn<<<dim3(128, 8), 256, 0, stream>>>(qkvb, ctx);
    k_gemm<32, 256, 0, 1><<<dim3(256, 1), 256, 0, stream>>>(  // out proj + add + LN1
        ctx, 256, outw_l, 256, outb_l, nullptr, src, srcb, 256, 256, 256, 0, 0,
        0, 0, nullptr, 0, 0, 0, 0, 0, 0, g1_l, b1_l);
    k_gemm<64, 128, 0><<<dim3(128, 9), 256, 0, stream>>>(   // lin1 + relu
        srcb, 256, l1w_l, 256, l1b_l, nullptr, nullptr, ff, 1152, 256, 1152, 1, 1,
        0, 0, GEMM_TAIL);
    k_gemm<32, 256, 0, 1><<<dim3(256, 1), 256, 0, stream>>>(  // lin2 + add + LN2
        ff, 1152, l2w_l, 1152, l2b_l, nullptr, src, srcb, 256, 1152, 256, 0, 0,
        0, 0, nullptr, 0, 0, 0, 0, 0, 0, g2_l, b2_l);
  }

  // ---- output ----
  k_nxc_to_cxn<<<dim3(8, 32, 8), dim3(32, 32), 0, stream>>>(src, (float*)d_out);
}